// Round 11
// baseline (291.728 us; speedup 1.0000x reference)
//
#include <hip/hip_runtime.h>
#include <hip/hip_bf16.h>

// DeepViT re-attention, fused flash-style two-pass.
//  k0 convert3 : x, w_qkv, w_out fp32 -> bf16 (ws)
//  k1 gemm_qkv : qkv = x @ w_qkv^T (bf16 MFMA); scatter q(scaled)/k/vT bf16
//  k2 passA    : softmax stats (m, l), j-split x4
//  k3 passB    : BARRIER-FREE wave-independent flash. Each wave owns
//                (i-tile-16, j-eighth-256, all 8 heads): QK^T (k=32 MFMA) ->
//                p in-lane -> mix+LN -> pack bf16 -> PV via k=16 MFMA whose
//                B-operand k-layout (k=lg*4+e) EQUALS the S^T lane layout ->
//                no LDS transpose, no per-iter barriers. pacc[8][4] f32x4
//                (128 regs) + ~96 working; waves_per_eu(2,2) budget 256.
//                End: 4-chunk LDS reduction over the block's 8 j-partials ->
//                bf16 inner store (no atomics / memset / convert kernel).
//  k4 gemm_out : out = inner @ w_out^T + b_out (fp32)

typedef __attribute__((ext_vector_type(8))) short bfx8;
typedef __attribute__((ext_vector_type(4))) short bfx4;
typedef __attribute__((ext_vector_type(4))) float f32x4;
typedef unsigned short u16;
typedef unsigned int u32;

#define QSCALE 0.18033688011112042f  /* (1/8) * log2(e) */

static __device__ inline u16 f2bf(float f) {
  union { float f; unsigned u; } cv; cv.f = f;
  unsigned u = cv.u;
  u += 0x7fffu + ((u >> 16) & 1u);   // RNE
  return (u16)(u >> 16);
}
static __device__ inline u32 cvtpk(float lo, float hi) {  // {bf16(lo), bf16(hi)}
  u32 d; asm("v_cvt_pk_bf16_f32 %0, %1, %2" : "=v"(d) : "v"(lo), "v"(hi)); return d;
}
static __device__ inline float fexp2(float x) {
  float r; asm("v_exp_f32 %0, %1" : "=v"(r) : "v"(x)); return r;
}
static __device__ inline float flog2(float x) {
  float r; asm("v_log_f32 %0, %1" : "=v"(r) : "v"(x)); return r;
}
// k=16 bf16 MFMA: lane(li,lg) A[m=li][k=lg*4+e], B[k=lg*4+e][n=li], C col=li row=lg*4+r
static __device__ inline f32x4 mfma16(bfx4 a, bfx4 b, f32x4 c) {
#if __has_builtin(__builtin_amdgcn_mfma_f32_16x16x16bf16_1k)
  return __builtin_amdgcn_mfma_f32_16x16x16bf16_1k(a, b, c, 0, 0, 0);
#else
  asm("v_mfma_f32_16x16x16_bf16 %0, %1, %2, %0" : "+v"(c) : "v"(a), "v"(b));
  return c;
#endif
}

// ---------------- k0: fp32 -> bf16 converts ----------------
__global__ __launch_bounds__(256) void convert3(
    const float* __restrict__ x, const float* __restrict__ wq,
    const float* __restrict__ wo,
    u16* __restrict__ xb, u16* __restrict__ wqb, u16* __restrict__ wob) {
  int e = (blockIdx.x * 256 + threadIdx.x) * 4;
  const float* src; u16* dst; int off;
  if (e < 2097152)      { src = x;  dst = xb;  off = e; }
  else if (e < 2883584) { src = wq; dst = wqb; off = e - 2097152; }
  else                  { src = wo; dst = wob; off = e - 2883584; }
  float4 v = *(const float4*)&src[off];
  ushort4 o; o.x = f2bf(v.x); o.y = f2bf(v.y); o.z = f2bf(v.z); o.w = f2bf(v.w);
  *(ushort4*)&dst[off] = o;
}

// ---------------- k1: bf16 GEMM, C = A @ B^T, QKV scatter epilogue ----------------
__global__ __launch_bounds__(256) void gemm_qkv(
    const u16* __restrict__ A, const u16* __restrict__ B,
    u16* __restrict__ qb, u16* __restrict__ kb, u16* __restrict__ vtb) {
  __shared__ u16 As[128 * 32];
  __shared__ u16 Bs[128 * 32];
  const int t = threadIdx.x, lane = t & 63;
  const int wm = (t >> 6) >> 1, wn = (t >> 6) & 1;
  const int m0 = blockIdx.y * 128, n0 = blockIdx.x * 128;
  const int li = lane & 15, lg = lane >> 4;
  const int rowA = t >> 2, kb8 = (t & 3) * 8;
  f32x4 acc[4][4] = {};
  for (int k0 = 0; k0 < 512; k0 += 32) {
    __syncthreads();
    *(bfx8*)&As[rowA * 32 + kb8]        = *(const bfx8*)&A[(size_t)(m0 + rowA) * 512 + k0 + kb8];
    *(bfx8*)&As[(rowA + 64) * 32 + kb8] = *(const bfx8*)&A[(size_t)(m0 + rowA + 64) * 512 + k0 + kb8];
    *(bfx8*)&Bs[rowA * 32 + kb8]        = *(const bfx8*)&B[(size_t)(n0 + rowA) * 512 + k0 + kb8];
    *(bfx8*)&Bs[(rowA + 64) * 32 + kb8] = *(const bfx8*)&B[(size_t)(n0 + rowA + 64) * 512 + k0 + kb8];
    __syncthreads();
    bfx8 af[4], bf_[4];
#pragma unroll
    for (int mi = 0; mi < 4; mi++)
      af[mi] = *(const bfx8*)&As[(wm * 64 + mi * 16 + li) * 32 + lg * 8];
#pragma unroll
    for (int ni = 0; ni < 4; ni++)
      bf_[ni] = *(const bfx8*)&Bs[(wn * 64 + ni * 16 + li) * 32 + lg * 8];
#pragma unroll
    for (int mi = 0; mi < 4; mi++)
#pragma unroll
      for (int ni = 0; ni < 4; ni++)
        acc[mi][ni] = __builtin_amdgcn_mfma_f32_16x16x32_bf16(af[mi], bf_[ni], acc[mi][ni], 0, 0, 0);
  }
#pragma unroll
  for (int mi = 0; mi < 4; mi++) {
#pragma unroll
    for (int ni = 0; ni < 4; ni++) {
      const int nc  = n0 + wn * 64 + ni * 16 + li;
      const int mrb = m0 + wm * 64 + mi * 16 + lg * 4;
      const int part = nc >> 9, within = nc & 511;
      const int h = within >> 6, d = within & 63;
      const int bb = mrb >> 11, ii = mrb & 2047;
      if (part == 0) {
#pragma unroll
        for (int r = 0; r < 4; r++)
          qb[(((size_t)bb * 8 + h) * 2048 + ii + r) * 64 + d] = f2bf(acc[mi][ni][r] * QSCALE);
      } else if (part == 1) {
#pragma unroll
        for (int r = 0; r < 4; r++)
          kb[(((size_t)bb * 8 + h) * 2048 + ii + r) * 64 + d] = f2bf(acc[mi][ni][r]);
      } else {
        ushort4 u;
        u.x = f2bf(acc[mi][ni][0]); u.y = f2bf(acc[mi][ni][1]);
        u.z = f2bf(acc[mi][ni][2]); u.w = f2bf(acc[mi][ni][3]);
        *(ushort4*)&vtb[(((size_t)bb * 8 + h) * 64 + d) * 2048 + ii] = u;
      }
    }
  }
}

// ---------------- k2: softmax stats (m, l), j-split x4, 2-tile batched ----------------
__global__ __launch_bounds__(256) void passA(
    const u16* __restrict__ qb, const u16* __restrict__ kb,
    float2* __restrict__ statp) {
  const int t = threadIdx.x, lane = t & 63, w = t >> 6;
  const int bh = blockIdx.y, js = blockIdx.z;
  const int i0 = blockIdx.x * 64 + w * 16;
  const int li = lane & 15, lg = lane >> 4;
  const u16* Qh = qb + ((size_t)bh * 2048 + i0 + li) * 64;
  const u16* Kb = kb + (size_t)bh * 2048 * 64;
  const bfx8 q0 = *(const bfx8*)&Qh[lg * 8];
  const bfx8 q1 = *(const bfx8*)&Qh[32 + lg * 8];
  float m = -1e30f, l = 0.f;
  const int jbeg = js * 512, jend = jbeg + 512;
  for (int j0 = jbeg; j0 < jend; j0 += 32) {
    const u16* KhA = Kb + (size_t)(j0 + li) * 64;
    const u16* KhB = KhA + 16 * 64;
    bfx8 a0 = *(const bfx8*)&KhA[lg * 8];
    bfx8 a1 = *(const bfx8*)&KhA[32 + lg * 8];
    bfx8 b0 = *(const bfx8*)&KhB[lg * 8];
    bfx8 b1 = *(const bfx8*)&KhB[32 + lg * 8];
    __builtin_amdgcn_sched_barrier(0);
    f32x4 sa = {0.f, 0.f, 0.f, 0.f}, sb = {0.f, 0.f, 0.f, 0.f};
    sa = __builtin_amdgcn_mfma_f32_16x16x32_bf16(a0, q0, sa, 0, 0, 0);
    sa = __builtin_amdgcn_mfma_f32_16x16x32_bf16(a1, q1, sa, 0, 0, 0);
    sb = __builtin_amdgcn_mfma_f32_16x16x32_bf16(b0, q0, sb, 0, 0, 0);
    sb = __builtin_amdgcn_mfma_f32_16x16x32_bf16(b1, q1, sb, 0, 0, 0);
    float mt = fmaxf(fmaxf(fmaxf(sa[0], sa[1]), fmaxf(sa[2], sa[3])),
                     fmaxf(fmaxf(sb[0], sb[1]), fmaxf(sb[2], sb[3])));
    float mn = fmaxf(m, mt);
    float es = (fexp2(sa[0] - mn) + fexp2(sa[1] - mn)) + (fexp2(sa[2] - mn) + fexp2(sa[3] - mn))
             + (fexp2(sb[0] - mn) + fexp2(sb[1] - mn)) + (fexp2(sb[2] - mn) + fexp2(sb[3] - mn));
    l = fmaf(l, fexp2(m - mn), es);
    m = mn;
  }
  for (int off = 16; off < 64; off <<= 1) {
    float mo = __shfl_xor(m, off, 64);
    float lo = __shfl_xor(l, off, 64);
    float mn = fmaxf(m, mo);
    l = l * fexp2(m - mn) + lo * fexp2(mo - mn);
    m = mn;
  }
  if (lane < 16) statp[(size_t)js * 32768 + (size_t)bh * 2048 + i0 + li] = make_float2(m, l);
}

// ---------------- k3: pass B — barrier-free wave-independent flash ----------------
// grid (128, 2): x = i-tile-of-16, y = b. 512 thr = 8 waves; wave w owns j-eighth.
__global__ __launch_bounds__(512) __attribute__((amdgpu_waves_per_eu(2, 2)))
void passB(
    const u16* __restrict__ qb, const u16* __restrict__ kb,
    const u16* __restrict__ vtb, const float2* __restrict__ statp,
    const float* __restrict__ Wmix, const float* __restrict__ lng,
    const float* __restrict__ lnb, u16* __restrict__ inner) {
  __shared__ __align__(16) u16 Qs[8 * 16 * 72];      // 18KB [h][i][d], d-pad +8
  __shared__ __align__(16) float Red[8 * 64 * 36];   // 72KB reduce buf (pad 32->36)
  const int t = threadIdx.x, lane = t & 63, w = t >> 6;
  const int b = blockIdx.y, i0 = blockIdx.x * 16;
  const int li = lane & 15, lg = lane >> 4;

  // stage Q: 1024 16B-chunks, 2 per thread
#pragma unroll
  for (int cc = 0; cc < 2; cc++) {
    const int c = t + cc * 512;
    const int h = c >> 7, qi = (c >> 3) & 15, d8 = c & 7;
    bfx8 v = *(const bfx8*)&qb[(((size_t)(b * 8 + h)) * 2048 + i0 + qi) * 64 + d8 * 8];
    *(bfx8*)&Qs[(h * 16 + qi) * 72 + d8 * 8] = v;
  }

  float wm_[8][8], lng_[8], lnb_[8];   // uniform -> SGPR
#pragma unroll
  for (int h = 0; h < 8; h++)
#pragma unroll
    for (int g = 0; g < 8; g++) wm_[h][g] = Wmix[h * 8 + g];
#pragma unroll
  for (int g = 0; g < 8; g++) { lng_[g] = lng[g]; lnb_[g] = lnb[g]; }

  // fused stats merge over 4 j-split partials: M = m + log2(l)
  float stM[8];
#pragma unroll
  for (int h = 0; h < 8; h++) {
    const size_t idx = ((size_t)(b * 8 + h)) * 2048 + i0 + li;
    float m = -1e30f, l = 0.f;
#pragma unroll
    for (int z = 0; z < 4; z++) {
      const float2 a = statp[(size_t)z * 32768 + idx];
      const float mn = fmaxf(m, a.x);
      l = l * fexp2(m - mn) + a.y * fexp2(a.x - mn);
      m = mn;
    }
    stM[h] = m + flog2(l);
  }

  __syncthreads();  // Qs ready — the ONLY barrier before the final reduction

  f32x4 pacc[8][4] = {};   // [head][d-tile] = O^T partial, 128 regs
  const size_t hstr = (size_t)2048 * 64;
  const int jb = w * 256;
  for (int j0 = jb; j0 < jb + 256; j0 += 16) {
    const u16* Kb0 = kb + ((size_t)(b * 8) * 2048 + j0 + li) * 64;
    float p[8][4];
    // QK^T: 2 half-batches of 4 heads, loads pinned ahead by sched_barrier
#pragma unroll
    for (int hb = 0; hb < 2; hb++) {
      bfx8 kf[4][2];
#pragma unroll
      for (int hh = 0; hh < 4; hh++) {
        const u16* Kh = Kb0 + (size_t)(hb * 4 + hh) * hstr;
        kf[hh][0] = *(const bfx8*)&Kh[lg * 8];
        kf[hh][1] = *(const bfx8*)&Kh[32 + lg * 8];
      }
      __builtin_amdgcn_sched_barrier(0);
#pragma unroll
      for (int hh = 0; hh < 4; hh++) {
        const int h = hb * 4 + hh;
        const bfx8 qA = *(const bfx8*)&Qs[(h * 16 + li) * 72 + lg * 8];
        const bfx8 qB = *(const bfx8*)&Qs[(h * 16 + li) * 72 + 32 + lg * 8];
        f32x4 s = {0.f, 0.f, 0.f, 0.f};
        s = __builtin_amdgcn_mfma_f32_16x16x32_bf16(kf[hh][0], qA, s, 0, 0, 0);
        s = __builtin_amdgcn_mfma_f32_16x16x32_bf16(kf[hh][1], qB, s, 0, 0, 0);
#pragma unroll
        for (int r = 0; r < 4; r++) p[h][r] = fexp2(s[r] - stM[h]);
      }
    }
    // 8x8 head mix + LN -> packed bf16 {r0,r1},{r2,r3} (= k=16 B-fragment)
    u32 apk[8][2];
    float tmp[8];
#pragma unroll
    for (int r = 0; r < 4; r++) {
      float a_[8]; float sum = 0.f, sumsq = 0.f;
#pragma unroll
      for (int g = 0; g < 8; g++) {
        float acc = 0.f;
#pragma unroll
        for (int h = 0; h < 8; h++) acc = fmaf(p[h][r], wm_[h][g], acc);
        a_[g] = acc; sum += acc; sumsq = fmaf(acc, acc, sumsq);
      }
      const float mu = sum * 0.125f;
      const float var = fmaf(sumsq, 0.125f, -mu * mu);
      const float rs = rsqrtf(var + 1e-5f);
#pragma unroll
      for (int g = 0; g < 8; g++) {
        const float av = fmaf((a_[g] - mu) * rs, lng_[g], lnb_[g]);
        if (r & 1) apk[g][r >> 1] = cvtpk(tmp[g], av);
        else       tmp[g] = av;
      }
    }
    // PV: k=16 MFMA, A = V^T fragment (8B direct load), B = packed A'' in-reg
#pragma unroll
    for (int h = 0; h < 8; h++) {
      const u16* Vh = vtb + ((size_t)(b * 8 + h)) * 64 * 2048 + j0 + lg * 4;
      union { u32 u[2]; bfx4 v; } bu;
      bu.u[0] = apk[h][0]; bu.u[1] = apk[h][1];
#pragma unroll
      for (int dt = 0; dt < 4; dt++) {
        const bfx4 va = *(const bfx4*)&Vh[(size_t)(dt * 16 + li) * 2048];
        pacc[h][dt] = mfma16(va, bu.v, pacc[h][dt]);
      }
    }
  }

  // block reduction over the 8 waves' j-partials: 4 chunks of 2 heads
#pragma unroll
  for (int hc = 0; hc < 4; hc++) {
    __syncthreads();   // Red free / all waves ready
#pragma unroll
    for (int hh = 0; hh < 2; hh++)
#pragma unroll
      for (int dt = 0; dt < 4; dt++)
        *(f32x4*)&Red[((size_t)w * 64 + lane) * 36 + (hh * 4 + dt) * 4] =
            pacc[hc * 2 + hh][dt];
    __syncthreads();
    {
      // thread t sums 8 partials of elements e = 4t..4t+3 of this 2048-chunk
      const int sl = t >> 3;             // source lane (0..63)
      const int rg = (t & 7) * 4;        // source reg base
      float4 s = {0.f, 0.f, 0.f, 0.f};
#pragma unroll
      for (int wv = 0; wv < 8; wv++) {
        const float4 v = *(const float4*)&Red[((size_t)wv * 64 + sl) * 36 + rg];
        s.x += v.x; s.y += v.y; s.z += v.z; s.w += v.w;
      }
      const int hh = (t >> 2) & 1, dt = t & 3;
      const int sli = (t >> 3) & 15, slg = t >> 7;
      const int h = hc * 2 + hh;
      u16* dst = inner + ((size_t)b * 2048 + i0 + sli) * 512 + h * 64 + dt * 16 + slg * 4;
      uint2 pk; pk.x = cvtpk(s.x, s.y); pk.y = cvtpk(s.z, s.w);
      *(uint2*)dst = pk;
    }
  }
}

// ---------------- k4: out = inner @ wo^T + b_out ----------------
__global__ __launch_bounds__(256) void gemm_out(
    const u16* __restrict__ A, const u16* __restrict__ B,
    float* __restrict__ outf, const float* __restrict__ bias) {
  __shared__ u16 As[128 * 32];
  __shared__ u16 Bs[128 * 32];
  const int t = threadIdx.x, lane = t & 63;
  const int wm = (t >> 6) >> 1, wn = (t >> 6) & 1;
  const int m0 = blockIdx.y * 128, n0 = blockIdx.x * 128;
  const int li = lane & 15, lg = lane >> 4;
  const int rowA = t >> 2, kb8 = (t & 3) * 8;
  f32x4 acc[4][4] = {};
  for (int k0 = 0; k0 < 512; k0 += 32) {
    __syncthreads();
    *(bfx8*)&As[rowA * 32 + kb8]        = *(const bfx8*)&A[(size_t)(m0 + rowA) * 512 + k0 + kb8];
    *(bfx8*)&As[(rowA + 64) * 32 + kb8] = *(const bfx8*)&A[(size_t)(m0 + rowA + 64) * 512 + k0 + kb8];
    *(bfx8*)&Bs[rowA * 32 + kb8]        = *(const bfx8*)&B[(size_t)(n0 + rowA) * 512 + k0 + kb8];
    *(bfx8*)&Bs[(rowA + 64) * 32 + kb8] = *(const bfx8*)&B[(size_t)(n0 + rowA + 64) * 512 + k0 + kb8];
    __syncthreads();
    bfx8 af[4], bf_[4];
#pragma unroll
    for (int mi = 0; mi < 4; mi++)
      af[mi] = *(const bfx8*)&As[(wm * 64 + mi * 16 + li) * 32 + lg * 8];
#pragma unroll
    for (int ni = 0; ni < 4; ni++)
      bf_[ni] = *(const bfx8*)&Bs[(wn * 64 + ni * 16 + li) * 32 + lg * 8];
#pragma unroll
    for (int mi = 0; mi < 4; mi++)
#pragma unroll
      for (int ni = 0; ni < 4; ni++)
        acc[mi][ni] = __builtin_amdgcn_mfma_f32_16x16x32_bf16(af[mi], bf_[ni], acc[mi][ni], 0, 0, 0);
  }
#pragma unroll
  for (int mi = 0; mi < 4; mi++) {
#pragma unroll
    for (int ni = 0; ni < 4; ni++) {
      const int nc  = n0 + wn * 64 + ni * 16 + li;
      const int mrb = m0 + wm * 64 + mi * 16 + lg * 4;
      const float bv = bias[nc];
#pragma unroll
      for (int r = 0; r < 4; r++)
        outf[(size_t)(mrb + r) * 512 + nc] = acc[mi][ni][r] + bv;
    }
  }
}

// ---------------- host ----------------
extern "C" void kernel_launch(void* const* d_in, const int* in_sizes, int n_in,
                              void* d_out, int out_size, void* d_ws, size_t ws_size,
                              hipStream_t stream) {
  const float* x      = (const float*)d_in[0];
  const float* w_qkv  = (const float*)d_in[1];
  const float* reattn = (const float*)d_in[2];
  const float* ln_g   = (const float*)d_in[3];
  const float* ln_b   = (const float*)d_in[4];
  const float* w_out  = (const float*)d_in[5];
  const float* b_out  = (const float*)d_in[6];
  float* out = (float*)d_out;
  char* ws = (char*)d_ws;
  // ws layout (bytes), ~22.3 MB:
  //  [0, 8388608)  : xb (0..4MB) + wqb (4..5.75MB) during k0/k1;
  //                  then inner bf16 [2,2048,512] at +0 (passB out, gemm_out in)
  u16*    xb    = (u16*)(ws + 0);
  u16*    wqb   = (u16*)(ws + 4194304);
  u16*    inner = (u16*)(ws + 0);
  u16*    qbf   = (u16*)(ws + 8388608);    // [2,8,2048,64] bf16 (scaled)
  u16*    kbf   = (u16*)(ws + 12582912);   // [2,8,2048,64] bf16
  u16*    vtb   = (u16*)(ws + 16777216);   // [2,8,64,2048] bf16
  float2* statp = (float2*)(ws + 20971520);// [4][2,8,2048] raw (m, l) partials
  u16*    wob   = (u16*)(ws + 22020096);   // 512x512 bf16

  convert3<<<3072, 256, 0, stream>>>(x, w_qkv, w_out, xb, wqb, wob);
  gemm_qkv<<<dim3(12, 32), 256, 0, stream>>>(xb, wqb, qbf, kbf, vtb);
  passA<<<dim3(32, 16, 4), 256, 0, stream>>>(qbf, kbf, statp);
  passB<<<dim3(128, 2), 512, 0, stream>>>(qbf, kbf, vtb, statp, reattn, ln_g, ln_b, inner);
  gemm_out<<<dim3(4, 32), 256, 0, stream>>>(inner, wob, out, b_out);
}

// Round 12
// 257.380 us; speedup vs baseline: 1.1335x; 1.1335x over previous
//
#include <hip/hip_runtime.h>
#include <hip/hip_bf16.h>

// DeepViT re-attention, fused flash-style two-pass.
//  k0 convert3 : x, w_qkv, w_out fp32 -> bf16 (ws)
//  k1 gemm_qkv : qkv = x @ w_qkv^T (bf16 MFMA); scatter q(scaled)/k/vT bf16
//  (memset)    : zero inner_f32 accumulator (reuses xb/wqb region)
//  k2 passA    : softmax stats (m, l), j-split x4
//  k3 passB    : R9 structure at 3 blocks/CU: grid (128,2,3) = 768 blocks
//                (exactly 3/CU, macro split 6/5/5), LDS 48KB (A2 32K + Qs 16K
//                XOR-swizzled, no pad) -> 3x48=144<=160KB; waves_per_eu(6,6)
//                -> ~85 VGPR budget (R9's 56 was too starved for ILP).
//                Occupancy target 75% (24 waves/CU) vs R9's 37%.
//  k3b convert : inner_f32 -> bf16
//  k4 gemm_out : out = inner @ w_out^T + b_out (fp32)

typedef __attribute__((ext_vector_type(8))) short bfx8;
typedef __attribute__((ext_vector_type(4))) float f32x4;
typedef unsigned short u16;
typedef unsigned int u32;

#define QSCALE 0.18033688011112042f  /* (1/8) * log2(e) */

static __device__ inline u16 f2bf(float f) {
  union { float f; unsigned u; } cv; cv.f = f;
  unsigned u = cv.u;
  u += 0x7fffu + ((u >> 16) & 1u);   // RNE
  return (u16)(u >> 16);
}
static __device__ inline u32 cvtpk(float lo, float hi) {  // {bf16(lo), bf16(hi)}
  u32 d; asm("v_cvt_pk_bf16_f32 %0, %1, %2" : "=v"(d) : "v"(lo), "v"(hi)); return d;
}
static __device__ inline float fexp2(float x) {
  float r; asm("v_exp_f32 %0, %1" : "=v"(r) : "v"(x)); return r;
}
static __device__ inline float flog2(float x) {
  float r; asm("v_log_f32 %0, %1" : "=v"(r) : "v"(x)); return r;
}

// ---------------- k0: fp32 -> bf16 converts ----------------
__global__ __launch_bounds__(256) void convert3(
    const float* __restrict__ x, const float* __restrict__ wq,
    const float* __restrict__ wo,
    u16* __restrict__ xb, u16* __restrict__ wqb, u16* __restrict__ wob) {
  int e = (blockIdx.x * 256 + threadIdx.x) * 4;
  const float* src; u16* dst; int off;
  if (e < 2097152)      { src = x;  dst = xb;  off = e; }
  else if (e < 2883584) { src = wq; dst = wqb; off = e - 2097152; }
  else                  { src = wo; dst = wob; off = e - 2883584; }
  float4 v = *(const float4*)&src[off];
  ushort4 o; o.x = f2bf(v.x); o.y = f2bf(v.y); o.z = f2bf(v.z); o.w = f2bf(v.w);
  *(ushort4*)&dst[off] = o;
}

// ---------------- k1: bf16 GEMM, C = A @ B^T, QKV scatter epilogue ----------------
__global__ __launch_bounds__(256) void gemm_qkv(
    const u16* __restrict__ A, const u16* __restrict__ B,
    u16* __restrict__ qb, u16* __restrict__ kb, u16* __restrict__ vtb) {
  __shared__ u16 As[128 * 32];
  __shared__ u16 Bs[128 * 32];
  const int t = threadIdx.x, lane = t & 63;
  const int wm = (t >> 6) >> 1, wn = (t >> 6) & 1;
  const int m0 = blockIdx.y * 128, n0 = blockIdx.x * 128;
  const int li = lane & 15, lg = lane >> 4;
  const int rowA = t >> 2, kb8 = (t & 3) * 8;
  f32x4 acc[4][4] = {};
  for (int k0 = 0; k0 < 512; k0 += 32) {
    __syncthreads();
    *(bfx8*)&As[rowA * 32 + kb8]        = *(const bfx8*)&A[(size_t)(m0 + rowA) * 512 + k0 + kb8];
    *(bfx8*)&As[(rowA + 64) * 32 + kb8] = *(const bfx8*)&A[(size_t)(m0 + rowA + 64) * 512 + k0 + kb8];
    *(bfx8*)&Bs[rowA * 32 + kb8]        = *(const bfx8*)&B[(size_t)(n0 + rowA) * 512 + k0 + kb8];
    *(bfx8*)&Bs[(rowA + 64) * 32 + kb8] = *(const bfx8*)&B[(size_t)(n0 + rowA + 64) * 512 + k0 + kb8];
    __syncthreads();
    bfx8 af[4], bf_[4];
#pragma unroll
    for (int mi = 0; mi < 4; mi++)
      af[mi] = *(const bfx8*)&As[(wm * 64 + mi * 16 + li) * 32 + lg * 8];
#pragma unroll
    for (int ni = 0; ni < 4; ni++)
      bf_[ni] = *(const bfx8*)&Bs[(wn * 64 + ni * 16 + li) * 32 + lg * 8];
#pragma unroll
    for (int mi = 0; mi < 4; mi++)
#pragma unroll
      for (int ni = 0; ni < 4; ni++)
        acc[mi][ni] = __builtin_amdgcn_mfma_f32_16x16x32_bf16(af[mi], bf_[ni], acc[mi][ni], 0, 0, 0);
  }
#pragma unroll
  for (int mi = 0; mi < 4; mi++) {
#pragma unroll
    for (int ni = 0; ni < 4; ni++) {
      const int nc  = n0 + wn * 64 + ni * 16 + li;
      const int mrb = m0 + wm * 64 + mi * 16 + lg * 4;
      const int part = nc >> 9, within = nc & 511;
      const int h = within >> 6, d = within & 63;
      const int bb = mrb >> 11, ii = mrb & 2047;
      if (part == 0) {
#pragma unroll
        for (int r = 0; r < 4; r++)
          qb[(((size_t)bb * 8 + h) * 2048 + ii + r) * 64 + d] = f2bf(acc[mi][ni][r] * QSCALE);
      } else if (part == 1) {
#pragma unroll
        for (int r = 0; r < 4; r++)
          kb[(((size_t)bb * 8 + h) * 2048 + ii + r) * 64 + d] = f2bf(acc[mi][ni][r]);
      } else {
        ushort4 u;
        u.x = f2bf(acc[mi][ni][0]); u.y = f2bf(acc[mi][ni][1]);
        u.z = f2bf(acc[mi][ni][2]); u.w = f2bf(acc[mi][ni][3]);
        *(ushort4*)&vtb[(((size_t)bb * 8 + h) * 64 + d) * 2048 + ii] = u;
      }
    }
  }
}

// ---------------- k2: softmax stats (m, l), j-split x4, 2-tile batched ----------------
__global__ __launch_bounds__(256) void passA(
    const u16* __restrict__ qb, const u16* __restrict__ kb,
    float2* __restrict__ statp) {
  const int t = threadIdx.x, lane = t & 63, w = t >> 6;
  const int bh = blockIdx.y, js = blockIdx.z;
  const int i0 = blockIdx.x * 64 + w * 16;
  const int li = lane & 15, lg = lane >> 4;
  const u16* Qh = qb + ((size_t)bh * 2048 + i0 + li) * 64;
  const u16* Kb = kb + (size_t)bh * 2048 * 64;
  const bfx8 q0 = *(const bfx8*)&Qh[lg * 8];
  const bfx8 q1 = *(const bfx8*)&Qh[32 + lg * 8];
  float m = -1e30f, l = 0.f;
  const int jbeg = js * 512, jend = jbeg + 512;
  for (int j0 = jbeg; j0 < jend; j0 += 32) {
    const u16* KhA = Kb + (size_t)(j0 + li) * 64;
    const u16* KhB = KhA + 16 * 64;
    bfx8 a0 = *(const bfx8*)&KhA[lg * 8];
    bfx8 a1 = *(const bfx8*)&KhA[32 + lg * 8];
    bfx8 b0 = *(const bfx8*)&KhB[lg * 8];
    bfx8 b1 = *(const bfx8*)&KhB[32 + lg * 8];
    __builtin_amdgcn_sched_barrier(0);
    f32x4 sa = {0.f, 0.f, 0.f, 0.f}, sb = {0.f, 0.f, 0.f, 0.f};
    sa = __builtin_amdgcn_mfma_f32_16x16x32_bf16(a0, q0, sa, 0, 0, 0);
    sa = __builtin_amdgcn_mfma_f32_16x16x32_bf16(a1, q1, sa, 0, 0, 0);
    sb = __builtin_amdgcn_mfma_f32_16x16x32_bf16(b0, q0, sb, 0, 0, 0);
    sb = __builtin_amdgcn_mfma_f32_16x16x32_bf16(b1, q1, sb, 0, 0, 0);
    float mt = fmaxf(fmaxf(fmaxf(sa[0], sa[1]), fmaxf(sa[2], sa[3])),
                     fmaxf(fmaxf(sb[0], sb[1]), fmaxf(sb[2], sb[3])));
    float mn = fmaxf(m, mt);
    float es = (fexp2(sa[0] - mn) + fexp2(sa[1] - mn)) + (fexp2(sa[2] - mn) + fexp2(sa[3] - mn))
             + (fexp2(sb[0] - mn) + fexp2(sb[1] - mn)) + (fexp2(sb[2] - mn) + fexp2(sb[3] - mn));
    l = fmaf(l, fexp2(m - mn), es);
    m = mn;
  }
  for (int off = 16; off < 64; off <<= 1) {
    float mo = __shfl_xor(m, off, 64);
    float lo = __shfl_xor(l, off, 64);
    float mn = fmaxf(m, mo);
    l = l * fexp2(m - mn) + lo * fexp2(mo - mn);
    m = mn;
  }
  if (lane < 16) statp[(size_t)js * 32768 + (size_t)bh * 2048 + i0 + li] = make_float2(m, l);
}

// ---------------- k3: pass B ----------------
// grid (128, 2, 3): x = i-tile-of-16, y = b, z = j-chunk (6/5/5 macros of 128).
// 512 thr = 8 waves. LDS 48KB -> 3 blocks/CU; waves_per_eu(6,6) -> ~85 VGPR.
__global__ __launch_bounds__(512) __attribute__((amdgpu_waves_per_eu(6, 6)))
void passB(
    const u16* __restrict__ qb, const u16* __restrict__ kb,
    const u16* __restrict__ vtb, const float2* __restrict__ statp,
    const float* __restrict__ Wmix, const float* __restrict__ lng,
    const float* __restrict__ lnb, float* __restrict__ innerF) {
  __shared__ __align__(16) u16 A2[8 * 16 * 128];  // 32KB [g][i][j], j XOR-swizzled
  __shared__ __align__(16) u16 Qs[8 * 16 * 64];   // 16KB [h][i][d], d XOR-swizzled
  const int t = threadIdx.x, lane = t & 63, w = t >> 6;
  const int b = blockIdx.y, i0 = blockIdx.x * 16;
  const int li = lane & 15, lg = lane >> 4;
  const int swz = (li & 7) << 3;

  // stage Q: 1024 16B-chunks, 2 per thread; col XOR-swizzled by row (qi&7)
#pragma unroll
  for (int cc = 0; cc < 2; cc++) {
    const int c = t + cc * 512;
    const int h = c >> 7, qi = (c >> 3) & 15, d8 = c & 7;
    bfx8 v = *(const bfx8*)&qb[(((size_t)(b * 8 + h)) * 2048 + i0 + qi) * 64 + d8 * 8];
    *(bfx8*)&Qs[(h * 16 + qi) * 64 + ((d8 * 8) ^ ((qi & 7) << 3))] = v;
  }

  float wm_[8][8], lng_[8], lnb_[8];   // uniform -> SGPR
#pragma unroll
  for (int h = 0; h < 8; h++)
#pragma unroll
    for (int g = 0; g < 8; g++) wm_[h][g] = Wmix[h * 8 + g];
#pragma unroll
  for (int g = 0; g < 8; g++) { lng_[g] = lng[g]; lnb_[g] = lnb[g]; }

  // fused stats merge over 4 j-split partials: M = m + log2(l)
  float stM[8];
#pragma unroll
  for (int h = 0; h < 8; h++) {
    const size_t idx = ((size_t)(b * 8 + h)) * 2048 + i0 + li;
    float m = -1e30f, l = 0.f;
#pragma unroll
    for (int z = 0; z < 4; z++) {
      const float2 a = statp[(size_t)z * 32768 + idx];
      const float mn = fmaxf(m, a.x);
      l = l * fexp2(m - mn) + a.y * fexp2(a.x - mn);
      m = mn;
    }
    stM[h] = m + flog2(l);
  }

  __syncthreads();  // Qs ready

  f32x4 pacc[4] = {};
  const int nmac = (blockIdx.z == 0) ? 6 : 5;
  const int jm0 = ((blockIdx.z == 0) ? 0 : (blockIdx.z == 1 ? 6 : 11)) * 128;
  const size_t hstr = (size_t)2048 * 64;
  const int qswz = (li & 7) << 3;
  for (int mc = 0; mc < nmac; mc++) {
    const int jm = jm0 + mc * 128;
    const int j0 = jm + w * 16;
    const u16* Kb0 = kb + ((size_t)(b * 8) * 2048 + j0 + li) * 64;
    float p[8][4];
    // 2 half-batches of 4 heads: 8 K-loads in flight, pinned by sched_barrier
#pragma unroll
    for (int hb = 0; hb < 2; hb++) {
      bfx8 kf[4][2];
#pragma unroll
      for (int hh = 0; hh < 4; hh++) {
        const u16* Kh = Kb0 + (size_t)(hb * 4 + hh) * hstr;
        kf[hh][0] = *(const bfx8*)&Kh[lg * 8];
        kf[hh][1] = *(const bfx8*)&Kh[32 + lg * 8];
      }
      __builtin_amdgcn_sched_barrier(0);
#pragma unroll
      for (int hh = 0; hh < 4; hh++) {
        const int h = hb * 4 + hh;
        const bfx8 qA = *(const bfx8*)&Qs[(h * 16 + li) * 64 + ((lg * 8) ^ qswz)];
        const bfx8 qB = *(const bfx8*)&Qs[(h * 16 + li) * 64 + ((32 + lg * 8) ^ qswz)];
        f32x4 s = {0.f, 0.f, 0.f, 0.f};
        s = __builtin_amdgcn_mfma_f32_16x16x32_bf16(kf[hh][0], qA, s, 0, 0, 0);
        s = __builtin_amdgcn_mfma_f32_16x16x32_bf16(kf[hh][1], qB, s, 0, 0, 0);
#pragma unroll
        for (int r = 0; r < 4; r++) p[h][r] = fexp2(s[r] - stM[h]);
      }
    }
    // 8x8 head mix + LN + cvt_pk packing
    u32 apk[8][2];
    float tmp[8];
#pragma unroll
    for (int r = 0; r < 4; r++) {
      float a_[8]; float sum = 0.f, sumsq = 0.f;
#pragma unroll
      for (int g = 0; g < 8; g++) {
        float acc = 0.f;
#pragma unroll
        for (int h = 0; h < 8; h++) acc = fmaf(p[h][r], wm_[h][g], acc);
        a_[g] = acc; sum += acc; sumsq = fmaf(acc, acc, sumsq);
      }
      const float mu = sum * 0.125f;
      const float var = fmaf(sumsq, 0.125f, -mu * mu);
      const float rs = rsqrtf(var + 1e-5f);
#pragma unroll
      for (int g = 0; g < 8; g++) {
        const float av = fmaf((a_[g] - mu) * rs, lng_[g], lnb_[g]);
        if (r & 1) apk[g][r >> 1] = cvtpk(tmp[g], av);
        else       tmp[g] = av;
      }
    }
    {
      const int jsw = (w * 16 + lg * 4) ^ swz;   // 4 consecutive j per lane
#pragma unroll
      for (int g = 0; g < 8; g++)
        *(uint2*)&A2[(g * 16 + li) * 128 + jsw] = make_uint2(apk[g][0], apk[g][1]);
    }
    __syncthreads();
    // PV: 2 half-batches (8 V loads in flight each), wave = head w
    const u16* Vh = vtb + ((size_t)(b * 8 + w)) * 64 * 2048 + jm;
#pragma unroll
    for (int kcc = 0; kcc < 2; kcc++) {
      bfx8 vF[2][4];
#pragma unroll
      for (int kc = 0; kc < 2; kc++)
#pragma unroll
        for (int nd = 0; nd < 4; nd++)
          vF[kc][nd] = *(const bfx8*)&Vh[(size_t)(nd * 16 + li) * 2048 + (kcc * 2 + kc) * 32 + lg * 8];
      __builtin_amdgcn_sched_barrier(0);
      __builtin_amdgcn_s_setprio(1);
#pragma unroll
      for (int kc = 0; kc < 2; kc++) {
        const bfx8 af = *(const bfx8*)&A2[(w * 16 + li) * 128 + (((kcc * 2 + kc) * 32 + lg * 8) ^ swz)];
#pragma unroll
        for (int nd = 0; nd < 4; nd++)
          pacc[nd] = __builtin_amdgcn_mfma_f32_16x16x32_bf16(af, vF[kc][nd], pacc[nd], 0, 0, 0);
      }
      __builtin_amdgcn_s_setprio(0);
    }
    __syncthreads();
  }
#pragma unroll
  for (int nd = 0; nd < 4; nd++)
#pragma unroll
    for (int r = 0; r < 4; r++)
      atomicAdd(&innerF[((size_t)b * 2048 + i0 + lg * 4 + r) * 512 + w * 64 + nd * 16 + li],
                pacc[nd][r]);
}

// ---------------- k3b: inner f32 -> bf16 ----------------
__global__ __launch_bounds__(256) void convertInner(
    const float* __restrict__ inF, u16* __restrict__ outB) {
  int e = (blockIdx.x * 256 + threadIdx.x) * 4;
  float4 v = *(const float4*)&inF[e];
  ushort4 o; o.x = f2bf(v.x); o.y = f2bf(v.y); o.z = f2bf(v.z); o.w = f2bf(v.w);
  *(ushort4*)&outB[e] = o;
}

// ---------------- k4: out = inner @ wo^T + b_out ----------------
__global__ __launch_bounds__(256) void gemm_out(
    const u16* __restrict__ A, const u16* __restrict__ B,
    float* __restrict__ outf, const float* __restrict__ bias) {
  __shared__ u16 As[128 * 32];
  __shared__ u16 Bs[128 * 32];
  const int t = threadIdx.x, lane = t & 63;
  const int wm = (t >> 6) >> 1, wn = (t >> 6) & 1;
  const int m0 = blockIdx.y * 128, n0 = blockIdx.x * 128;
  const int li = lane & 15, lg = lane >> 4;
  const int rowA = t >> 2, kb8 = (t & 3) * 8;
  f32x4 acc[4][4] = {};
  for (int k0 = 0; k0 < 512; k0 += 32) {
    __syncthreads();
    *(bfx8*)&As[rowA * 32 + kb8]        = *(const bfx8*)&A[(size_t)(m0 + rowA) * 512 + k0 + kb8];
    *(bfx8*)&As[(rowA + 64) * 32 + kb8] = *(const bfx8*)&A[(size_t)(m0 + rowA + 64) * 512 + k0 + kb8];
    *(bfx8*)&Bs[rowA * 32 + kb8]        = *(const bfx8*)&B[(size_t)(n0 + rowA) * 512 + k0 + kb8];
    *(bfx8*)&Bs[(rowA + 64) * 32 + kb8] = *(const bfx8*)&B[(size_t)(n0 + rowA + 64) * 512 + k0 + kb8];
    __syncthreads();
    bfx8 af[4], bf_[4];
#pragma unroll
    for (int mi = 0; mi < 4; mi++)
      af[mi] = *(const bfx8*)&As[(wm * 64 + mi * 16 + li) * 32 + lg * 8];
#pragma unroll
    for (int ni = 0; ni < 4; ni++)
      bf_[ni] = *(const bfx8*)&Bs[(wn * 64 + ni * 16 + li) * 32 + lg * 8];
#pragma unroll
    for (int mi = 0; mi < 4; mi++)
#pragma unroll
      for (int ni = 0; ni < 4; ni++)
        acc[mi][ni] = __builtin_amdgcn_mfma_f32_16x16x32_bf16(af[mi], bf_[ni], acc[mi][ni], 0, 0, 0);
  }
#pragma unroll
  for (int mi = 0; mi < 4; mi++) {
#pragma unroll
    for (int ni = 0; ni < 4; ni++) {
      const int nc  = n0 + wn * 64 + ni * 16 + li;
      const int mrb = m0 + wm * 64 + mi * 16 + lg * 4;
      const float bv = bias[nc];
#pragma unroll
      for (int r = 0; r < 4; r++)
        outf[(size_t)(mrb + r) * 512 + nc] = acc[mi][ni][r] + bv;
    }
  }
}

// ---------------- host ----------------
extern "C" void kernel_launch(void* const* d_in, const int* in_sizes, int n_in,
                              void* d_out, int out_size, void* d_ws, size_t ws_size,
                              hipStream_t stream) {
  const float* x      = (const float*)d_in[0];
  const float* w_qkv  = (const float*)d_in[1];
  const float* reattn = (const float*)d_in[2];
  const float* ln_g   = (const float*)d_in[3];
  const float* ln_b   = (const float*)d_in[4];
  const float* w_out  = (const float*)d_in[5];
  const float* b_out  = (const float*)d_in[6];
  float* out = (float*)d_out;
  char* ws = (char*)d_ws;
  // ws layout (bytes), ~22.5 MB:
  //  [0, 8388608)  : xb + wqb during k0/k1; then innerF f32 (zeroed after k1).
  //  innerB bf16 reuses qbf region after passB completes.
  u16*    xb    = (u16*)(ws + 0);
  u16*    wqb   = (u16*)(ws + 4194304);
  float*  innerF= (float*)(ws + 0);
  u16*    qbf   = (u16*)(ws + 8388608);    // [2,8,2048,64] bf16 (scaled)
  u16*    kbf   = (u16*)(ws + 12582912);   // [2,8,2048,64] bf16
  u16*    vtb   = (u16*)(ws + 16777216);   // [2,8,64,2048] bf16
  float2* statp = (float2*)(ws + 20971520);// [4][2,8,2048] raw (m, l) partials
  u16*    wob   = (u16*)(ws + 22020096);   // 512x512 bf16
  u16*    innerB= (u16*)(ws + 8388608);    // reuses qbf after passB

  convert3<<<3072, 256, 0, stream>>>(x, w_qkv, w_out, xb, wqb, wob);
  gemm_qkv<<<dim3(12, 32), 256, 0, stream>>>(xb, wqb, qbf, kbf, vtb);
  hipMemsetAsync(innerF, 0, 8388608, stream);
  passA<<<dim3(32, 16, 4), 256, 0, stream>>>(qbf, kbf, statp);
  passB<<<dim3(128, 2, 3), 512, 0, stream>>>(qbf, kbf, vtb, statp, reattn, ln_g, ln_b, innerF);
  convertInner<<<2048, 256, 0, stream>>>(innerF, innerB);
  gemm_out<<<dim3(4, 32), 256, 0, stream>>>(innerB, wob, out, b_out);
}

// Round 13
// 241.886 us; speedup vs baseline: 1.2061x; 1.0641x over previous
//
#include <hip/hip_runtime.h>
#include <hip/hip_bf16.h>

// DeepViT re-attention, fused flash-style two-pass.
//  k0 convert3 : x, w_qkv, w_out fp32 -> bf16 (ws)
//  k1 gemm_qkv : qkv = x @ w_qkv^T (bf16 MFMA); scatter q(scaled)/k/vT bf16
//  k2 passA    : softmax stats (m, l), j-split x4
//  k3 passB    : SOFTWARE-PIPELINED, 1 block/CU, grid (128,2)=256 blocks.
//                All 16 V fragments issued at TOP of each macro-iter (pinned
//                by sched_barrier) -> V latency hides under QK^T+mix (~1700cy).
//                K half-batches overlap each other. Full j=2048 per block ->
//                direct bf16 store (no atomics / memset / convert kernel).
//                waves_per_eu(2): ~196 VGPR/wave wanted; occupancy knobs are
//                counterproductive (R2/R3/R7/R12: squeeze -> spill, never ILP).
//  k4 gemm_out : out = inner @ w_out^T + b_out (fp32)

typedef __attribute__((ext_vector_type(8))) short bfx8;
typedef __attribute__((ext_vector_type(4))) float f32x4;
typedef unsigned short u16;
typedef unsigned int u32;

#define QSCALE 0.18033688011112042f  /* (1/8) * log2(e) */

static __device__ inline u16 f2bf(float f) {
  union { float f; unsigned u; } cv; cv.f = f;
  unsigned u = cv.u;
  u += 0x7fffu + ((u >> 16) & 1u);   // RNE
  return (u16)(u >> 16);
}
static __device__ inline u32 cvtpk(float lo, float hi) {  // {bf16(lo), bf16(hi)}
  u32 d; asm("v_cvt_pk_bf16_f32 %0, %1, %2" : "=v"(d) : "v"(lo), "v"(hi)); return d;
}
static __device__ inline float fexp2(float x) {
  float r; asm("v_exp_f32 %0, %1" : "=v"(r) : "v"(x)); return r;
}
static __device__ inline float flog2(float x) {
  float r; asm("v_log_f32 %0, %1" : "=v"(r) : "v"(x)); return r;
}

// ---------------- k0: fp32 -> bf16 converts ----------------
__global__ __launch_bounds__(256) void convert3(
    const float* __restrict__ x, const float* __restrict__ wq,
    const float* __restrict__ wo,
    u16* __restrict__ xb, u16* __restrict__ wqb, u16* __restrict__ wob) {
  int e = (blockIdx.x * 256 + threadIdx.x) * 4;
  const float* src; u16* dst; int off;
  if (e < 2097152)      { src = x;  dst = xb;  off = e; }
  else if (e < 2883584) { src = wq; dst = wqb; off = e - 2097152; }
  else                  { src = wo; dst = wob; off = e - 2883584; }
  float4 v = *(const float4*)&src[off];
  ushort4 o; o.x = f2bf(v.x); o.y = f2bf(v.y); o.z = f2bf(v.z); o.w = f2bf(v.w);
  *(ushort4*)&dst[off] = o;
}

// ---------------- k1: bf16 GEMM, C = A @ B^T, QKV scatter epilogue ----------------
__global__ __launch_bounds__(256) void gemm_qkv(
    const u16* __restrict__ A, const u16* __restrict__ B,
    u16* __restrict__ qb, u16* __restrict__ kb, u16* __restrict__ vtb) {
  __shared__ u16 As[128 * 32];
  __shared__ u16 Bs[128 * 32];
  const int t = threadIdx.x, lane = t & 63;
  const int wm = (t >> 6) >> 1, wn = (t >> 6) & 1;
  const int m0 = blockIdx.y * 128, n0 = blockIdx.x * 128;
  const int li = lane & 15, lg = lane >> 4;
  const int rowA = t >> 2, kb8 = (t & 3) * 8;
  f32x4 acc[4][4] = {};
  for (int k0 = 0; k0 < 512; k0 += 32) {
    __syncthreads();
    *(bfx8*)&As[rowA * 32 + kb8]        = *(const bfx8*)&A[(size_t)(m0 + rowA) * 512 + k0 + kb8];
    *(bfx8*)&As[(rowA + 64) * 32 + kb8] = *(const bfx8*)&A[(size_t)(m0 + rowA + 64) * 512 + k0 + kb8];
    *(bfx8*)&Bs[rowA * 32 + kb8]        = *(const bfx8*)&B[(size_t)(n0 + rowA) * 512 + k0 + kb8];
    *(bfx8*)&Bs[(rowA + 64) * 32 + kb8] = *(const bfx8*)&B[(size_t)(n0 + rowA + 64) * 512 + k0 + kb8];
    __syncthreads();
    bfx8 af[4], bf_[4];
#pragma unroll
    for (int mi = 0; mi < 4; mi++)
      af[mi] = *(const bfx8*)&As[(wm * 64 + mi * 16 + li) * 32 + lg * 8];
#pragma unroll
    for (int ni = 0; ni < 4; ni++)
      bf_[ni] = *(const bfx8*)&Bs[(wn * 64 + ni * 16 + li) * 32 + lg * 8];
#pragma unroll
    for (int mi = 0; mi < 4; mi++)
#pragma unroll
      for (int ni = 0; ni < 4; ni++)
        acc[mi][ni] = __builtin_amdgcn_mfma_f32_16x16x32_bf16(af[mi], bf_[ni], acc[mi][ni], 0, 0, 0);
  }
#pragma unroll
  for (int mi = 0; mi < 4; mi++) {
#pragma unroll
    for (int ni = 0; ni < 4; ni++) {
      const int nc  = n0 + wn * 64 + ni * 16 + li;
      const int mrb = m0 + wm * 64 + mi * 16 + lg * 4;
      const int part = nc >> 9, within = nc & 511;
      const int h = within >> 6, d = within & 63;
      const int bb = mrb >> 11, ii = mrb & 2047;
      if (part == 0) {
#pragma unroll
        for (int r = 0; r < 4; r++)
          qb[(((size_t)bb * 8 + h) * 2048 + ii + r) * 64 + d] = f2bf(acc[mi][ni][r] * QSCALE);
      } else if (part == 1) {
#pragma unroll
        for (int r = 0; r < 4; r++)
          kb[(((size_t)bb * 8 + h) * 2048 + ii + r) * 64 + d] = f2bf(acc[mi][ni][r]);
      } else {
        ushort4 u;
        u.x = f2bf(acc[mi][ni][0]); u.y = f2bf(acc[mi][ni][1]);
        u.z = f2bf(acc[mi][ni][2]); u.w = f2bf(acc[mi][ni][3]);
        *(ushort4*)&vtb[(((size_t)bb * 8 + h) * 64 + d) * 2048 + ii] = u;
      }
    }
  }
}

// ---------------- k2: softmax stats (m, l), j-split x4, 2-tile batched ----------------
__global__ __launch_bounds__(256) void passA(
    const u16* __restrict__ qb, const u16* __restrict__ kb,
    float2* __restrict__ statp) {
  const int t = threadIdx.x, lane = t & 63, w = t >> 6;
  const int bh = blockIdx.y, js = blockIdx.z;
  const int i0 = blockIdx.x * 64 + w * 16;
  const int li = lane & 15, lg = lane >> 4;
  const u16* Qh = qb + ((size_t)bh * 2048 + i0 + li) * 64;
  const u16* Kb = kb + (size_t)bh * 2048 * 64;
  const bfx8 q0 = *(const bfx8*)&Qh[lg * 8];
  const bfx8 q1 = *(const bfx8*)&Qh[32 + lg * 8];
  float m = -1e30f, l = 0.f;
  const int jbeg = js * 512, jend = jbeg + 512;
  for (int j0 = jbeg; j0 < jend; j0 += 32) {
    const u16* KhA = Kb + (size_t)(j0 + li) * 64;
    const u16* KhB = KhA + 16 * 64;
    bfx8 a0 = *(const bfx8*)&KhA[lg * 8];
    bfx8 a1 = *(const bfx8*)&KhA[32 + lg * 8];
    bfx8 b0 = *(const bfx8*)&KhB[lg * 8];
    bfx8 b1 = *(const bfx8*)&KhB[32 + lg * 8];
    __builtin_amdgcn_sched_barrier(0);
    f32x4 sa = {0.f, 0.f, 0.f, 0.f}, sb = {0.f, 0.f, 0.f, 0.f};
    sa = __builtin_amdgcn_mfma_f32_16x16x32_bf16(a0, q0, sa, 0, 0, 0);
    sa = __builtin_amdgcn_mfma_f32_16x16x32_bf16(a1, q1, sa, 0, 0, 0);
    sb = __builtin_amdgcn_mfma_f32_16x16x32_bf16(b0, q0, sb, 0, 0, 0);
    sb = __builtin_amdgcn_mfma_f32_16x16x32_bf16(b1, q1, sb, 0, 0, 0);
    float mt = fmaxf(fmaxf(fmaxf(sa[0], sa[1]), fmaxf(sa[2], sa[3])),
                     fmaxf(fmaxf(sb[0], sb[1]), fmaxf(sb[2], sb[3])));
    float mn = fmaxf(m, mt);
    float es = (fexp2(sa[0] - mn) + fexp2(sa[1] - mn)) + (fexp2(sa[2] - mn) + fexp2(sa[3] - mn))
             + (fexp2(sb[0] - mn) + fexp2(sb[1] - mn)) + (fexp2(sb[2] - mn) + fexp2(sb[3] - mn));
    l = fmaf(l, fexp2(m - mn), es);
    m = mn;
  }
  for (int off = 16; off < 64; off <<= 1) {
    float mo = __shfl_xor(m, off, 64);
    float lo = __shfl_xor(l, off, 64);
    float mn = fmaxf(m, mo);
    l = l * fexp2(m - mn) + lo * fexp2(mo - mn);
    m = mn;
  }
  if (lane < 16) statp[(size_t)js * 32768 + (size_t)bh * 2048 + i0 + li] = make_float2(m, l);
}

// ---------------- k3: pass B — software-pipelined, 1 block/CU ----------------
// grid (128, 2): x = i-tile-of-16, y = b. 512 thr = 8 waves; full j=2048.
__global__ __launch_bounds__(512) __attribute__((amdgpu_waves_per_eu(2)))
void passB(
    const u16* __restrict__ qb, const u16* __restrict__ kb,
    const u16* __restrict__ vtb, const float2* __restrict__ statp,
    const float* __restrict__ Wmix, const float* __restrict__ lng,
    const float* __restrict__ lnb, u16* __restrict__ inner) {
  __shared__ __align__(16) u16 A2[8 * 16 * 128];  // 32KB [g][i][j], j XOR-swizzled
  __shared__ __align__(16) u16 Qs[8 * 16 * 72];   // 18KB [h][i][d], d-pad +8 (2-way free)
  const int t = threadIdx.x, lane = t & 63, w = t >> 6;
  const int b = blockIdx.y, i0 = blockIdx.x * 16;
  const int li = lane & 15, lg = lane >> 4;
  const int swz = (li & 7) << 3;

  // stage Q: 1024 16B-chunks, 2 per thread
#pragma unroll
  for (int cc = 0; cc < 2; cc++) {
    const int c = t + cc * 512;
    const int h = c >> 7, qi = (c >> 3) & 15, d8 = c & 7;
    bfx8 v = *(const bfx8*)&qb[(((size_t)(b * 8 + h)) * 2048 + i0 + qi) * 64 + d8 * 8];
    *(bfx8*)&Qs[(h * 16 + qi) * 72 + d8 * 8] = v;
  }

  float wm_[8][8], lng_[8], lnb_[8];   // uniform -> SGPR
#pragma unroll
  for (int h = 0; h < 8; h++)
#pragma unroll
    for (int g = 0; g < 8; g++) wm_[h][g] = Wmix[h * 8 + g];
#pragma unroll
  for (int g = 0; g < 8; g++) { lng_[g] = lng[g]; lnb_[g] = lnb[g]; }

  // fused stats merge over 4 j-split partials: M = m + log2(l)
  float stM[8];
#pragma unroll
  for (int h = 0; h < 8; h++) {
    const size_t idx = ((size_t)(b * 8 + h)) * 2048 + i0 + li;
    float m = -1e30f, l = 0.f;
#pragma unroll
    for (int z = 0; z < 4; z++) {
      const float2 a = statp[(size_t)z * 32768 + idx];
      const float mn = fmaxf(m, a.x);
      l = l * fexp2(m - mn) + a.y * fexp2(a.x - mn);
      m = mn;
    }
    stM[h] = m + flog2(l);
  }

  __syncthreads();  // Qs ready

  f32x4 pacc[4] = {};
  const size_t hstr = (size_t)2048 * 64;
  const u16* Vh = vtb + ((size_t)(b * 8 + w)) * 64 * 2048;
  for (int jm = 0; jm < 2048; jm += 128) {
    // ---- V PREFETCH: all 16 fragments issued first, pinned by sched_barrier.
    // Depends only on jm -> ~1700cy of QK^T+mix hides the latency.
    bfx8 vF[4][4];
#pragma unroll
    for (int kc = 0; kc < 4; kc++)
#pragma unroll
      for (int nd = 0; nd < 4; nd++)
        vF[kc][nd] = *(const bfx8*)&Vh[(size_t)(nd * 16 + li) * 2048 + jm + kc * 32 + lg * 8];
    __builtin_amdgcn_sched_barrier(0);

    const int j0 = jm + w * 16;
    const u16* Kb0 = kb + ((size_t)(b * 8) * 2048 + j0 + li) * 64;
    float p[8][4];
    // QK^T: 2 half-batches of 4 heads (hb1's loads may hoist over hb0 compute)
#pragma unroll
    for (int hb = 0; hb < 2; hb++) {
      bfx8 kf[4][2];
#pragma unroll
      for (int hh = 0; hh < 4; hh++) {
        const u16* Kh = Kb0 + (size_t)(hb * 4 + hh) * hstr;
        kf[hh][0] = *(const bfx8*)&Kh[lg * 8];
        kf[hh][1] = *(const bfx8*)&Kh[32 + lg * 8];
      }
      __builtin_amdgcn_sched_barrier(0);
#pragma unroll
      for (int hh = 0; hh < 4; hh++) {
        const int h = hb * 4 + hh;
        const bfx8 qA = *(const bfx8*)&Qs[(h * 16 + li) * 72 + lg * 8];
        const bfx8 qB = *(const bfx8*)&Qs[(h * 16 + li) * 72 + 32 + lg * 8];
        f32x4 s = {0.f, 0.f, 0.f, 0.f};
        s = __builtin_amdgcn_mfma_f32_16x16x32_bf16(kf[hh][0], qA, s, 0, 0, 0);
        s = __builtin_amdgcn_mfma_f32_16x16x32_bf16(kf[hh][1], qB, s, 0, 0, 0);
#pragma unroll
        for (int r = 0; r < 4; r++) p[h][r] = fexp2(s[r] - stM[h]);
      }
    }
    // 8x8 head mix + LN + cvt_pk packing
    u32 apk[8][2];
    float tmp[8];
#pragma unroll
    for (int r = 0; r < 4; r++) {
      float a_[8]; float sum = 0.f, sumsq = 0.f;
#pragma unroll
      for (int g = 0; g < 8; g++) {
        float acc = 0.f;
#pragma unroll
        for (int h = 0; h < 8; h++) acc = fmaf(p[h][r], wm_[h][g], acc);
        a_[g] = acc; sum += acc; sumsq = fmaf(acc, acc, sumsq);
      }
      const float mu = sum * 0.125f;
      const float var = fmaf(sumsq, 0.125f, -mu * mu);
      const float rs = rsqrtf(var + 1e-5f);
#pragma unroll
      for (int g = 0; g < 8; g++) {
        const float av = fmaf((a_[g] - mu) * rs, lng_[g], lnb_[g]);
        if (r & 1) apk[g][r >> 1] = cvtpk(tmp[g], av);
        else       tmp[g] = av;
      }
    }
    {
      const int jsw = (w * 16 + lg * 4) ^ swz;   // 4 consecutive j per lane
#pragma unroll
      for (int g = 0; g < 8; g++)
        *(uint2*)&A2[(g * 16 + li) * 128 + jsw] = make_uint2(apk[g][0], apk[g][1]);
    }
    __syncthreads();
    // PV: V already resident in vF; A2 reads + 16 MFMA back-to-back
    __builtin_amdgcn_s_setprio(1);
#pragma unroll
    for (int kc = 0; kc < 4; kc++) {
      const bfx8 af = *(const bfx8*)&A2[(w * 16 + li) * 128 + ((kc * 32 + lg * 8) ^ swz)];
#pragma unroll
      for (int nd = 0; nd < 4; nd++)
        pacc[nd] = __builtin_amdgcn_mfma_f32_16x16x32_bf16(af, vF[kc][nd], pacc[nd], 0, 0, 0);
    }
    __builtin_amdgcn_s_setprio(0);
    __syncthreads();
  }
  // direct bf16 store (full j accumulated -> no partials)
  u16* dst = inner + ((size_t)b * 2048 + i0) * 512 + w * 64;
#pragma unroll
  for (int nd = 0; nd < 4; nd++)
#pragma unroll
    for (int r = 0; r < 4; r++)
      dst[(lg * 4 + r) * 512 + nd * 16 + li] = f2bf(pacc[nd][r]);
}

// ---------------- k4: out = inner @ wo^T + b_out ----------------
__global__ __launch_bounds__(256) void gemm_out(
    const u16* __restrict__ A, const u16* __restrict__ B,
    float* __restrict__ outf, const float* __restrict__ bias) {
  __shared__ u16 As[128 * 32];
  __shared__ u16 Bs[128 * 32];
  const int t = threadIdx.x, lane = t & 63;
  const int wm = (t >> 6) >> 1, wn = (t >> 6) & 1;
  const int m0 = blockIdx.y * 128, n0 = blockIdx.x * 128;
  const int li = lane & 15, lg = lane >> 4;
  const int rowA = t >> 2, kb8 = (t & 3) * 8;
  f32x4 acc[4][4] = {};
  for (int k0 = 0; k0 < 512; k0 += 32) {
    __syncthreads();
    *(bfx8*)&As[rowA * 32 + kb8]        = *(const bfx8*)&A[(size_t)(m0 + rowA) * 512 + k0 + kb8];
    *(bfx8*)&As[(rowA + 64) * 32 + kb8] = *(const bfx8*)&A[(size_t)(m0 + rowA + 64) * 512 + k0 + kb8];
    *(bfx8*)&Bs[rowA * 32 + kb8]        = *(const bfx8*)&B[(size_t)(n0 + rowA) * 512 + k0 + kb8];
    *(bfx8*)&Bs[(rowA + 64) * 32 + kb8] = *(const bfx8*)&B[(size_t)(n0 + rowA + 64) * 512 + k0 + kb8];
    __syncthreads();
    bfx8 af[4], bf_[4];
#pragma unroll
    for (int mi = 0; mi < 4; mi++)
      af[mi] = *(const bfx8*)&As[(wm * 64 + mi * 16 + li) * 32 + lg * 8];
#pragma unroll
    for (int ni = 0; ni < 4; ni++)
      bf_[ni] = *(const bfx8*)&Bs[(wn * 64 + ni * 16 + li) * 32 + lg * 8];
#pragma unroll
    for (int mi = 0; mi < 4; mi++)
#pragma unroll
      for (int ni = 0; ni < 4; ni++)
        acc[mi][ni] = __builtin_amdgcn_mfma_f32_16x16x32_bf16(af[mi], bf_[ni], acc[mi][ni], 0, 0, 0);
  }
#pragma unroll
  for (int mi = 0; mi < 4; mi++) {
#pragma unroll
    for (int ni = 0; ni < 4; ni++) {
      const int nc  = n0 + wn * 64 + ni * 16 + li;
      const int mrb = m0 + wm * 64 + mi * 16 + lg * 4;
      const float bv = bias[nc];
#pragma unroll
      for (int r = 0; r < 4; r++)
        outf[(size_t)(mrb + r) * 512 + nc] = acc[mi][ni][r] + bv;
    }
  }
}

// ---------------- host ----------------
extern "C" void kernel_launch(void* const* d_in, const int* in_sizes, int n_in,
                              void* d_out, int out_size, void* d_ws, size_t ws_size,
                              hipStream_t stream) {
  const float* x      = (const float*)d_in[0];
  const float* w_qkv  = (const float*)d_in[1];
  const float* reattn = (const float*)d_in[2];
  const float* ln_g   = (const float*)d_in[3];
  const float* ln_b   = (const float*)d_in[4];
  const float* w_out  = (const float*)d_in[5];
  const float* b_out  = (const float*)d_in[6];
  float* out = (float*)d_out;
  char* ws = (char*)d_ws;
  // ws layout (bytes), ~21.5 MB:
  //  [0, 8388608)  : xb (0..4MB) + wqb (4..5.75MB) during k0/k1;
  //                  then inner bf16 [2,2048,512] at +0 (passB out, gemm_out in)
  u16*    xb    = (u16*)(ws + 0);
  u16*    wqb   = (u16*)(ws + 4194304);
  u16*    inner = (u16*)(ws + 0);
  u16*    qbf   = (u16*)(ws + 8388608);    // [2,8,2048,64] bf16 (scaled)
  u16*    kbf   = (u16*)(ws + 12582912);   // [2,8,2048,64] bf16
  u16*    vtb   = (u16*)(ws + 16777216);   // [2,8,64,2048] bf16
  float2* statp = (float2*)(ws + 20971520);// [4][2,8,2048] raw (m, l) partials
  u16*    wob   = (u16*)(ws + 22020096);   // 512x512 bf16

  convert3<<<3072, 256, 0, stream>>>(x, w_qkv, w_out, xb, wqb, wob);
  gemm_qkv<<<dim3(12, 32), 256, 0, stream>>>(xb, wqb, qbf, kbf, vtb);
  passA<<<dim3(32, 16, 4), 256, 0, stream>>>(qbf, kbf, statp);
  passB<<<dim3(128, 2), 512, 0, stream>>>(qbf, kbf, vtb, statp, reattn, ln_g, ln_b, inner);
  gemm_out<<<dim3(4, 32), 256, 0, stream>>>(inner, wob, out, b_out);
}

// Round 15
// 204.489 us; speedup vs baseline: 1.4266x; 1.1829x over previous
//
#include <hip/hip_runtime.h>
#include <hip/hip_bf16.h>

// DeepViT re-attention — fused S-in-LDS pipeline.
//  k0 conv3   : x, w_qkv, w_out fp32 -> bf16
//  k1 gemm_qkv: qkv = x @ w_qkv^T; scatter q(scaled)/k/vT bf16
//  (memset)   : zero innerF f32 accumulator
//  k2 passA   : softmax stats (m, l), j-split x4
//  k3 kFused  : block = (64 i, b, j-quarter 512), 8 waves, wave = head.
//               Per 64-j tile: QK^T 64x64 in regs (16 MFMA) -> p=exp2(s-M)
//               bf16 -> LDS Spk[i][h][x]; mix+LN pointwise from LDS ->
//               A2h[g][i][x]; PV 16 MFMA. LDS 138KB, 1 block/CU.
//               f32 atomicAdd partials (4 j-quarters).
//  k4 convertInner, k5 gemm_out

typedef __attribute__((ext_vector_type(8))) short bfx8;
typedef __attribute__((ext_vector_type(4))) float f32x4;
typedef unsigned short u16;
typedef unsigned int u32;

#define QSCALE 0.18033688011112042f  /* (1/8) * log2(e) */

static __device__ inline u16 f2bf(float f) {
  union { float f; unsigned u; } cv; cv.f = f;
  unsigned u = cv.u;
  u += 0x7fffu + ((u >> 16) & 1u);   // RNE
  return (u16)(u >> 16);
}
static __device__ inline u32 cvtpk(float lo, float hi) {  // {bf16(lo), bf16(hi)}
  u32 d; asm("v_cvt_pk_bf16_f32 %0, %1, %2" : "=v"(d) : "v"(lo), "v"(hi)); return d;
}
static __device__ inline float fexp2(float x) {
  float r; asm("v_exp_f32 %0, %1" : "=v"(r) : "v"(x)); return r;
}
static __device__ inline float flog2(float x) {
  float r; asm("v_log_f32 %0, %1" : "=v"(r) : "v"(x)); return r;
}

// ---------------- k0: fp32 -> bf16 converts ----------------
__global__ __launch_bounds__(256) void convert3(
    const float* __restrict__ x, const float* __restrict__ wq,
    const float* __restrict__ wo,
    u16* __restrict__ xb, u16* __restrict__ wqb, u16* __restrict__ wob) {
  int e = (blockIdx.x * 256 + threadIdx.x) * 4;
  const float* src; u16* dst; int off;
  if (e < 2097152)      { src = x;  dst = xb;  off = e; }
  else if (e < 2883584) { src = wq; dst = wqb; off = e - 2097152; }
  else                  { src = wo; dst = wob; off = e - 2883584; }
  float4 v = *(const float4*)&src[off];
  ushort4 o; o.x = f2bf(v.x); o.y = f2bf(v.y); o.z = f2bf(v.z); o.w = f2bf(v.w);
  *(ushort4*)&dst[off] = o;
}

// ---------------- k1: bf16 GEMM, C = A @ B^T, QKV scatter epilogue ----------------
__global__ __launch_bounds__(256) void gemm_qkv(
    const u16* __restrict__ A, const u16* __restrict__ B,
    u16* __restrict__ qb, u16* __restrict__ kb, u16* __restrict__ vtb) {
  __shared__ u16 As[128 * 32];
  __shared__ u16 Bs[128 * 32];
  const int t = threadIdx.x, lane = t & 63;
  const int wm = (t >> 6) >> 1, wn = (t >> 6) & 1;
  const int m0 = blockIdx.y * 128, n0 = blockIdx.x * 128;
  const int li = lane & 15, lg = lane >> 4;
  const int rowA = t >> 2, kb8 = (t & 3) * 8;
  f32x4 acc[4][4] = {};
  for (int k0 = 0; k0 < 512; k0 += 32) {
    __syncthreads();
    *(bfx8*)&As[rowA * 32 + kb8]        = *(const bfx8*)&A[(size_t)(m0 + rowA) * 512 + k0 + kb8];
    *(bfx8*)&As[(rowA + 64) * 32 + kb8] = *(const bfx8*)&A[(size_t)(m0 + rowA + 64) * 512 + k0 + kb8];
    *(bfx8*)&Bs[rowA * 32 + kb8]        = *(const bfx8*)&B[(size_t)(n0 + rowA) * 512 + k0 + kb8];
    *(bfx8*)&Bs[(rowA + 64) * 32 + kb8] = *(const bfx8*)&B[(size_t)(n0 + rowA + 64) * 512 + k0 + kb8];
    __syncthreads();
    bfx8 af[4], bf_[4];
#pragma unroll
    for (int mi = 0; mi < 4; mi++)
      af[mi] = *(const bfx8*)&As[(wm * 64 + mi * 16 + li) * 32 + lg * 8];
#pragma unroll
    for (int ni = 0; ni < 4; ni++)
      bf_[ni] = *(const bfx8*)&Bs[(wn * 64 + ni * 16 + li) * 32 + lg * 8];
#pragma unroll
    for (int mi = 0; mi < 4; mi++)
#pragma unroll
      for (int ni = 0; ni < 4; ni++)
        acc[mi][ni] = __builtin_amdgcn_mfma_f32_16x16x32_bf16(af[mi], bf_[ni], acc[mi][ni], 0, 0, 0);
  }
#pragma unroll
  for (int mi = 0; mi < 4; mi++) {
#pragma unroll
    for (int ni = 0; ni < 4; ni++) {
      const int nc  = n0 + wn * 64 + ni * 16 + li;
      const int mrb = m0 + wm * 64 + mi * 16 + lg * 4;
      const int part = nc >> 9, within = nc & 511;
      const int h = within >> 6, d = within & 63;
      const int bb = mrb >> 11, ii = mrb & 2047;
      if (part == 0) {
#pragma unroll
        for (int r = 0; r < 4; r++)
          qb[(((size_t)bb * 8 + h) * 2048 + ii + r) * 64 + d] = f2bf(acc[mi][ni][r] * QSCALE);
      } else if (part == 1) {
#pragma unroll
        for (int r = 0; r < 4; r++)
          kb[(((size_t)bb * 8 + h) * 2048 + ii + r) * 64 + d] = f2bf(acc[mi][ni][r]);
      } else {
        ushort4 u;
        u.x = f2bf(acc[mi][ni][0]); u.y = f2bf(acc[mi][ni][1]);
        u.z = f2bf(acc[mi][ni][2]); u.w = f2bf(acc[mi][ni][3]);
        *(ushort4*)&vtb[(((size_t)bb * 8 + h) * 64 + d) * 2048 + ii] = u;
      }
    }
  }
}

// ---------------- k2: softmax stats (m, l), j-split x4 ----------------
__global__ __launch_bounds__(256) void passA(
    const u16* __restrict__ qb, const u16* __restrict__ kb,
    float2* __restrict__ statp) {
  const int t = threadIdx.x, lane = t & 63, w = t >> 6;
  const int bh = blockIdx.y, js = blockIdx.z;
  const int i0 = blockIdx.x * 64 + w * 16;
  const int li = lane & 15, lg = lane >> 4;
  const u16* Qh = qb + ((size_t)bh * 2048 + i0 + li) * 64;
  const u16* Kb = kb + (size_t)bh * 2048 * 64;
  const bfx8 q0 = *(const bfx8*)&Qh[lg * 8];
  const bfx8 q1 = *(const bfx8*)&Qh[32 + lg * 8];
  float m = -1e30f, l = 0.f;
  const int jbeg = js * 512, jend = jbeg + 512;
  for (int j0 = jbeg; j0 < jend; j0 += 32) {
    const u16* KhA = Kb + (size_t)(j0 + li) * 64;
    const u16* KhB = KhA + 16 * 64;
    bfx8 a0 = *(const bfx8*)&KhA[lg * 8];
    bfx8 a1 = *(const bfx8*)&KhA[32 + lg * 8];
    bfx8 b0 = *(const bfx8*)&KhB[lg * 8];
    bfx8 b1 = *(const bfx8*)&KhB[32 + lg * 8];
    __builtin_amdgcn_sched_barrier(0);
    f32x4 sa = {0.f, 0.f, 0.f, 0.f}, sb = {0.f, 0.f, 0.f, 0.f};
    sa = __builtin_amdgcn_mfma_f32_16x16x32_bf16(a0, q0, sa, 0, 0, 0);
    sa = __builtin_amdgcn_mfma_f32_16x16x32_bf16(a1, q1, sa, 0, 0, 0);
    sb = __builtin_amdgcn_mfma_f32_16x16x32_bf16(b0, q0, sb, 0, 0, 0);
    sb = __builtin_amdgcn_mfma_f32_16x16x32_bf16(b1, q1, sb, 0, 0, 0);
    float mt = fmaxf(fmaxf(fmaxf(sa[0], sa[1]), fmaxf(sa[2], sa[3])),
                     fmaxf(fmaxf(sb[0], sb[1]), fmaxf(sb[2], sb[3])));
    float mn = fmaxf(m, mt);
    float es = (fexp2(sa[0] - mn) + fexp2(sa[1] - mn)) + (fexp2(sa[2] - mn) + fexp2(sa[3] - mn))
             + (fexp2(sb[0] - mn) + fexp2(sb[1] - mn)) + (fexp2(sb[2] - mn) + fexp2(sb[3] - mn));
    l = fmaf(l, fexp2(m - mn), es);
    m = mn;
  }
  for (int off = 16; off < 64; off <<= 1) {
    float mo = __shfl_xor(m, off, 64);
    float lo = __shfl_xor(l, off, 64);
    float mn = fmaxf(m, mo);
    l = l * fexp2(m - mn) + lo * fexp2(mo - mn);
    m = mn;
  }
  if (lane < 16) statp[(size_t)js * 32768 + (size_t)bh * 2048 + i0 + li] = make_float2(m, l);
}

// ---------------- k3: kFused — QK^T + softmax + mix + LN + PV, S in LDS ----------------
// grid (32 i-tiles of 64, 2 b, 4 j-quarters), 512 thr = 8 waves, wave = head.
__global__ __launch_bounds__(512) void kFused(
    const u16* __restrict__ qb, const u16* __restrict__ kb,
    const u16* __restrict__ vtb, const float2* __restrict__ statp,
    const float* __restrict__ Wmix, const float* __restrict__ lng,
    const float* __restrict__ lnb, float* __restrict__ innerF) {
  __shared__ __align__(16) u16 Spk[64 * 512];     // 64KB  p bf16 [i][h][x]
  __shared__ __align__(16) u16 A2h[8 * 64 * 72];  // 72KB  A'' bf16 [g][i][x]
  __shared__ float stMs[64 * 8];                  // 2KB   M = m+log2(l) [i][h]
  const int t = threadIdx.x, lane = t & 63, w = t >> 6;
  const int li = lane & 15, lg = lane >> 4;
  const int ig = blockIdx.x * 64, b = blockIdx.y, j0 = blockIdx.z * 512;

  float wm_[8][8], lng_[8], lnb_[8];   // uniform -> SGPR
#pragma unroll
  for (int h = 0; h < 8; h++)
#pragma unroll
    for (int g = 0; g < 8; g++) wm_[h][g] = Wmix[h * 8 + g];
#pragma unroll
  for (int g = 0; g < 8; g++) { lng_[g] = lng[g]; lnb_[g] = lnb[g]; }

  // stats merge -> stMs[i][h]
  {
    const int i = t >> 3, h = t & 7;
    const size_t idx = ((size_t)(b * 8 + h)) * 2048 + ig + i;
    float m = -1e30f, l = 0.f;
#pragma unroll
    for (int z = 0; z < 4; z++) {
      const float2 a = statp[(size_t)z * 32768 + idx];
      const float mn = fmaxf(m, a.x);
      l = l * fexp2(m - mn) + a.y * fexp2(a.x - mn);
      m = mn;
    }
    stMs[i * 8 + h] = m + flog2(l);
  }

  // Q fragments for head w (held in regs for the whole block)
  bfx8 qf[4][2];
#pragma unroll
  for (int ii = 0; ii < 4; ii++)
#pragma unroll
    for (int ks = 0; ks < 2; ks++)
      qf[ii][ks] = *(const bfx8*)&qb[(((size_t)(b * 8 + w)) * 2048 + ig + ii * 16 + li) * 64
                                     + ks * 32 + lg * 8];
  __syncthreads();
  float stMp[4];
#pragma unroll
  for (int ii = 0; ii < 4; ii++) stMp[ii] = stMs[(ii * 16 + li) * 8 + w];

  f32x4 pacc[4][4] = {};
  const int mixI = t >> 3, mixJ8 = (t & 7) * 8;   // mix-phase position base
  const int mixSwz = (mixI & 7) << 3;
  for (int jt = j0; jt < j0 + 512; jt += 64) {
    // V prefetch (ks=0 half) — independent of everything before PV
    bfx8 vf0[4];
#pragma unroll
    for (int dt = 0; dt < 4; dt++)
      vf0[dt] = *(const bfx8*)&vtb[(((size_t)(b * 8 + w)) * 64 + dt * 16 + li) * 2048
                                   + jt + lg * 8];
    __builtin_amdgcn_sched_barrier(0);
    // K fragments for this j-tile
    bfx8 kf[4][2];
#pragma unroll
    for (int ji = 0; ji < 4; ji++)
#pragma unroll
      for (int ks = 0; ks < 2; ks++)
        kf[ji][ks] = *(const bfx8*)&kb[(((size_t)(b * 8 + w)) * 2048 + jt + ji * 16 + li) * 64
                                       + ks * 32 + lg * 8];
    __builtin_amdgcn_sched_barrier(0);
    // QK^T + exp + pack to Spk.  A=K (m=j), B=Q (n=i):
    // element: j = jt + ji*16 + lg*4 + r,  i = ii*16 + li.
#pragma unroll
    for (int ii = 0; ii < 4; ii++) {
      f32x4 s[4] = {};
#pragma unroll
      for (int ji = 0; ji < 4; ji++) {
        s[ji] = __builtin_amdgcn_mfma_f32_16x16x32_bf16(kf[ji][0], qf[ii][0], s[ji], 0, 0, 0);
        s[ji] = __builtin_amdgcn_mfma_f32_16x16x32_bf16(kf[ji][1], qf[ii][1], s[ji], 0, 0, 0);
      }
      const int i = ii * 16 + li;
      const int swzI = (i & 7) << 3;
#pragma unroll
      for (int ji = 0; ji < 4; ji++) {
        const float p0 = fexp2(s[ji][0] - stMp[ii]);
        const float p1 = fexp2(s[ji][1] - stMp[ii]);
        const float p2 = fexp2(s[ji][2] - stMp[ii]);
        const float p3 = fexp2(s[ji][3] - stMp[ii]);
        const int x = (ji * 16 + lg * 4) ^ swzI;
        *(uint2*)&Spk[i * 512 + w * 64 + x] = make_uint2(cvtpk(p0, p1), cvtpk(p2, p3));
      }
    }
    __syncthreads();
    // MIX + LN: thread handles 8 positions (i = mixI, j = jt + mixJ8 + 0..7)
    {
      u32 ogw[8][4];
      float tmp[8];
#pragma unroll
      for (int hf = 0; hf < 2; hf++) {
        float p[8][4];
#pragma unroll
        for (int h = 0; h < 8; h++) {
          const int x4 = (mixJ8 + hf * 4) ^ mixSwz;
          const uint2 v = *(const uint2*)&Spk[mixI * 512 + h * 64 + x4];
          union { u32 u; float f; } c0, c1, c2, c3;
          c0.u = v.x << 16; c1.u = v.x & 0xffff0000u;
          c2.u = v.y << 16; c3.u = v.y & 0xffff0000u;
          p[h][0] = c0.f; p[h][1] = c1.f; p[h][2] = c2.f; p[h][3] = c3.f;
        }
#pragma unroll
        for (int e = 0; e < 4; e++) {
          float a_[8]; float sum = 0.f, sumsq = 0.f;
#pragma unroll
          for (int g = 0; g < 8; g++) {
            float acc = 0.f;
#pragma unroll
            for (int h = 0; h < 8; h++) acc = fmaf(p[h][e], wm_[h][g], acc);
            a_[g] = acc; sum += acc; sumsq = fmaf(acc, acc, sumsq);
          }
          const float mu = sum * 0.125f;
          const float var = fmaf(sumsq, 0.125f, -mu * mu);
          const float rs = rsqrtf(var + 1e-5f);
#pragma unroll
          for (int g = 0; g < 8; g++) {
            const float av = fmaf((a_[g] - mu) * rs, lng_[g], lnb_[g]);
            if (e & 1) ogw[g][hf * 2 + (e >> 1)] = cvtpk(tmp[g], av);
            else       tmp[g] = av;
          }
        }
      }
#pragma unroll
      for (int g = 0; g < 8; g++)
        *(uint4*)&A2h[g * 4608 + mixI * 72 + (mixJ8 ^ mixSwz)] =
            make_uint4(ogw[g][0], ogw[g][1], ogw[g][2], ogw[g][3]);
    }
    __syncthreads();
    // PV: head w; A = A''[i][j] from A2h, B = V[d][j]
    bfx8 vf1[4];
#pragma unroll
    for (int dt = 0; dt < 4; dt++)
      vf1[dt] = *(const bfx8*)&vtb[(((size_t)(b * 8 + w)) * 64 + dt * 16 + li) * 2048
                                   + jt + 32 + lg * 8];
    __builtin_amdgcn_sched_barrier(0);
    __builtin_amdgcn_s_setprio(1);
#pragma unroll
    for (int iSub = 0; iSub < 4; iSub++) {
      const bfx8 af0 = *(const bfx8*)&A2h[w * 4608 + (iSub * 16 + li) * 72
                                          + ((lg * 8) ^ ((li & 7) << 3))];
#pragma unroll
      for (int dt = 0; dt < 4; dt++)
        pacc[iSub][dt] = __builtin_amdgcn_mfma_f32_16x16x32_bf16(af0, vf0[dt], pacc[iSub][dt], 0, 0, 0);
    }
#pragma unroll
    for (int iSub = 0; iSub < 4; iSub++) {
      const bfx8 af1 = *(const bfx8*)&A2h[w * 4608 + (iSub * 16 + li) * 72
                                          + ((32 + lg * 8) ^ ((li & 7) << 3))];
#pragma unroll
      for (int dt = 0; dt < 4; dt++)
        pacc[iSub][dt] = __builtin_amdgcn_mfma_f32_16x16x32_bf16(af1, vf1[dt], pacc[iSub][dt], 0, 0, 0);
    }
    __builtin_amdgcn_s_setprio(0);
    __syncthreads();
  }
  // epilogue: f32 atomic partials (4 j-quarter contributions per element)
#pragma unroll
  for (int iSub = 0; iSub < 4; iSub++)
#pragma unroll
    for (int dt = 0; dt < 4; dt++)
#pragma unroll
      for (int r = 0; r < 4; r++)
        atomicAdd(&innerF[((size_t)b * 2048 + ig + iSub * 16 + lg * 4 + r) * 512
                          + w * 64 + dt * 16 + li],
                  pacc[iSub][dt][r]);
}

// ---------------- k4: inner f32 -> bf16 ----------------
__global__ __launch_bounds__(256) void convertInner(
    const float* __restrict__ inF, u16* __restrict__ outB) {
  int e = (blockIdx.x * 256 + threadIdx.x) * 4;
  float4 v = *(const float4*)&inF[e];
  ushort4 o; o.x = f2bf(v.x); o.y = f2bf(v.y); o.z = f2bf(v.z); o.w = f2bf(v.w);
  *(ushort4*)&outB[e] = o;
}

// ---------------- k5: out = inner @ wo^T + b_out ----------------
__global__ __launch_bounds__(256) void gemm_out(
    const u16* __restrict__ A, const u16* __restrict__ B,
    float* __restrict__ outf, const float* __restrict__ bias) {
  __shared__ u16 As[128 * 32];
  __shared__ u16 Bs[128 * 32];
  const int t = threadIdx.x, lane = t & 63;
  const int wm = (t >> 6) >> 1, wn = (t >> 6) & 1;
  const int m0 = blockIdx.y * 128, n0 = blockIdx.x * 128;
  const int li = lane & 15, lg = lane >> 4;
  const int rowA = t >> 2, kb8 = (t & 3) * 8;
  f32x4 acc[4][4] = {};
  for (int k0 = 0; k0 < 512; k0 += 32) {
    __syncthreads();
    *(bfx8*)&As[rowA * 32 + kb8]        = *(const bfx8*)&A[(size_t)(m0 + rowA) * 512 + k0 + kb8];
    *(bfx8*)&As[(rowA + 64) * 32 + kb8] = *(const bfx8*)&A[(size_t)(m0 + rowA + 64) * 512 + k0 + kb8];
    *(bfx8*)&Bs[rowA * 32 + kb8]        = *(const bfx8*)&B[(size_t)(n0 + rowA) * 512 + k0 + kb8];
    *(bfx8*)&Bs[(rowA + 64) * 32 + kb8] = *(const bfx8*)&B[(size_t)(n0 + rowA + 64) * 512 + k0 + kb8];
    __syncthreads();
    bfx8 af[4], bf_[4];
#pragma unroll
    for (int mi = 0; mi < 4; mi++)
      af[mi] = *(const bfx8*)&As[(wm * 64 + mi * 16 + li) * 32 + lg * 8];
#pragma unroll
    for (int ni = 0; ni < 4; ni++)
      bf_[ni] = *(const bfx8*)&Bs[(wn * 64 + ni * 16 + li) * 32 + lg * 8];
#pragma unroll
    for (int mi = 0; mi < 4; mi++)
#pragma unroll
      for (int ni = 0; ni < 4; ni++)
        acc[mi][ni] = __builtin_amdgcn_mfma_f32_16x16x32_bf16(af[mi], bf_[ni], acc[mi][ni], 0, 0, 0);
  }
#pragma unroll
  for (int mi = 0; mi < 4; mi++) {
#pragma unroll
    for (int ni = 0; ni < 4; ni++) {
      const int nc  = n0 + wn * 64 + ni * 16 + li;
      const int mrb = m0 + wm * 64 + mi * 16 + lg * 4;
      const float bv = bias[nc];
#pragma unroll
      for (int r = 0; r < 4; r++)
        outf[(size_t)(mrb + r) * 512 + nc] = acc[mi][ni][r] + bv;
    }
  }
}

// ---------------- host ----------------
extern "C" void kernel_launch(void* const* d_in, const int* in_sizes, int n_in,
                              void* d_out, int out_size, void* d_ws, size_t ws_size,
                              hipStream_t stream) {
  const float* x      = (const float*)d_in[0];
  const float* w_qkv  = (const float*)d_in[1];
  const float* reattn = (const float*)d_in[2];
  const float* ln_g   = (const float*)d_in[3];
  const float* ln_b   = (const float*)d_in[4];
  const float* w_out  = (const float*)d_in[5];
  const float* b_out  = (const float*)d_in[6];
  float* out = (float*)d_out;
  char* ws = (char*)d_ws;
  // ws layout (bytes), ~21.5 MB (proven budget):
  //  [0, 8388608)  : xb + wqb during k0/k1; then innerF f32 (zeroed after k1).
  //  innerB bf16 reuses qbf region after kFused completes.
  u16*    xb    = (u16*)(ws + 0);
  u16*    wqb   = (u16*)(ws + 4194304);
  float*  innerF= (float*)(ws + 0);
  u16*    qbf   = (u16*)(ws + 8388608);    // [2,8,2048,64] bf16 (scaled)
  u16*    kbf   = (u16*)(ws + 12582912);   // [2,8,2048,64] bf16
  u16*    vtb   = (u16*)(ws + 16777216);   // [2,8,64,2048] bf16
  float2* statp = (float2*)(ws + 20971520);// [4][2,8,2048] raw (m, l) partials
  u16*    wob   = (u16*)(ws + 22020096);   // 512x512 bf16
  u16*    innerB= (u16*)(ws + 8388608);    // reuses qbf after kFused

  convert3<<<3072, 256, 0, stream>>>(x, w_qkv, w_out, xb, wqb, wob);
  gemm_qkv<<<dim3(12, 32), 256, 0, stream>>>(xb, wqb, qbf, kbf, vtb);
  hipMemsetAsync(innerF, 0, 8388608, stream);
  passA<<<dim3(32, 16, 4), 256, 0, stream>>>(qbf, kbf, statp);
  kFused<<<dim3(32, 2, 4), 512, 0, stream>>>(qbf, kbf, vtb, statp, reattn, ln_g, ln_b, innerF);
  convertInner<<<2048, 256, 0, stream>>>(innerF, innerB);
  gemm_out<<<dim3(4, 32), 256, 0, stream>>>(innerB, wob, out, b_out);
}

// Round 16
// 197.706 us; speedup vs baseline: 1.4756x; 1.0343x over previous
//
#include <hip/hip_runtime.h>
#include <hip/hip_bf16.h>

// DeepViT re-attention — fused S-in-LDS pipeline, v2.
//  k1 gemm_qkv: qkv = x @ w_qkv^T; f32 inputs stage-converted to bf16 in LDS
//               (convert3 kernel eliminated); scatter q(scaled)/k/vT bf16
//  (memset)   : zero innerF f32 accumulator
//  k2 passA   : softmax stats (m, l), j-split x4
//  k3 kFused  : block = (64 i, b, j-quarter 512), 8 waves, wave = head.
//               Per 64-j tile: QK^T 64x64 in regs -> p bf16 -> LDS Spk;
//               mix+LN from LDS -> A2h; PV. CROSS-TILE PREFETCH: K(t+1) and
//               V-half2(t) issued before mix (~1300cy) — 2 waves/SIMD has
//               256-reg budget, ~232 used. f32 atomicAdd partials.
//  k4 convertInner, k5 gemm_out (B = w_out f32, stage-converted)

typedef __attribute__((ext_vector_type(8))) short bfx8;
typedef __attribute__((ext_vector_type(4))) float f32x4;
typedef unsigned short u16;
typedef unsigned int u32;

#define QSCALE 0.18033688011112042f  /* (1/8) * log2(e) */

static __device__ inline u16 f2bf(float f) {
  union { float f; unsigned u; } cv; cv.f = f;
  unsigned u = cv.u;
  u += 0x7fffu + ((u >> 16) & 1u);   // RNE
  return (u16)(u >> 16);
}
static __device__ inline u32 cvtpk(float lo, float hi) {  // {bf16(lo), bf16(hi)}
  u32 d; asm("v_cvt_pk_bf16_f32 %0, %1, %2" : "=v"(d) : "v"(lo), "v"(hi)); return d;
}
static __device__ inline float fexp2(float x) {
  float r; asm("v_exp_f32 %0, %1" : "=v"(r) : "v"(x)); return r;
}
static __device__ inline float flog2(float x) {
  float r; asm("v_log_f32 %0, %1" : "=v"(r) : "v"(x)); return r;
}
static __device__ inline uint4 pk8(const float* p) {  // 8 f32 -> 8 bf16 (uint4)
  float4 a = *(const float4*)p, b = *(const float4*)(p + 4);
  return make_uint4(cvtpk(a.x, a.y), cvtpk(a.z, a.w), cvtpk(b.x, b.y), cvtpk(b.z, b.w));
}

// ---------------- k1: GEMM C = A @ B^T with f32->bf16 stage-convert ----------------
__global__ __launch_bounds__(256) void gemm_qkv(
    const float* __restrict__ A, const float* __restrict__ B,
    u16* __restrict__ qb, u16* __restrict__ kb, u16* __restrict__ vtb) {
  __shared__ u16 As[128 * 32];
  __shared__ u16 Bs[128 * 32];
  const int t = threadIdx.x, lane = t & 63;
  const int wm = (t >> 6) >> 1, wn = (t >> 6) & 1;
  const int m0 = blockIdx.y * 128, n0 = blockIdx.x * 128;
  const int li = lane & 15, lg = lane >> 4;
  const int rowA = t >> 2, kb8 = (t & 3) * 8;
  f32x4 acc[4][4] = {};
  for (int k0 = 0; k0 < 512; k0 += 32) {
    __syncthreads();
    *(uint4*)&As[rowA * 32 + kb8]        = pk8(&A[(size_t)(m0 + rowA) * 512 + k0 + kb8]);
    *(uint4*)&As[(rowA + 64) * 32 + kb8] = pk8(&A[(size_t)(m0 + rowA + 64) * 512 + k0 + kb8]);
    *(uint4*)&Bs[rowA * 32 + kb8]        = pk8(&B[(size_t)(n0 + rowA) * 512 + k0 + kb8]);
    *(uint4*)&Bs[(rowA + 64) * 32 + kb8] = pk8(&B[(size_t)(n0 + rowA + 64) * 512 + k0 + kb8]);
    __syncthreads();
    bfx8 af[4], bf_[4];
#pragma unroll
    for (int mi = 0; mi < 4; mi++)
      af[mi] = *(const bfx8*)&As[(wm * 64 + mi * 16 + li) * 32 + lg * 8];
#pragma unroll
    for (int ni = 0; ni < 4; ni++)
      bf_[ni] = *(const bfx8*)&Bs[(wn * 64 + ni * 16 + li) * 32 + lg * 8];
#pragma unroll
    for (int mi = 0; mi < 4; mi++)
#pragma unroll
      for (int ni = 0; ni < 4; ni++)
        acc[mi][ni] = __builtin_amdgcn_mfma_f32_16x16x32_bf16(af[mi], bf_[ni], acc[mi][ni], 0, 0, 0);
  }
#pragma unroll
  for (int mi = 0; mi < 4; mi++) {
#pragma unroll
    for (int ni = 0; ni < 4; ni++) {
      const int nc  = n0 + wn * 64 + ni * 16 + li;
      const int mrb = m0 + wm * 64 + mi * 16 + lg * 4;
      const int part = nc >> 9, within = nc & 511;
      const int h = within >> 6, d = within & 63;
      const int bb = mrb >> 11, ii = mrb & 2047;
      if (part == 0) {
#pragma unroll
        for (int r = 0; r < 4; r++)
          qb[(((size_t)bb * 8 + h) * 2048 + ii + r) * 64 + d] = f2bf(acc[mi][ni][r] * QSCALE);
      } else if (part == 1) {
#pragma unroll
        for (int r = 0; r < 4; r++)
          kb[(((size_t)bb * 8 + h) * 2048 + ii + r) * 64 + d] = f2bf(acc[mi][ni][r]);
      } else {
        ushort4 u;
        u.x = f2bf(acc[mi][ni][0]); u.y = f2bf(acc[mi][ni][1]);
        u.z = f2bf(acc[mi][ni][2]); u.w = f2bf(acc[mi][ni][3]);
        *(ushort4*)&vtb[(((size_t)bb * 8 + h) * 64 + d) * 2048 + ii] = u;
      }
    }
  }
}

// ---------------- k2: softmax stats (m, l), j-split x4 ----------------
__global__ __launch_bounds__(256) void passA(
    const u16* __restrict__ qb, const u16* __restrict__ kb,
    float2* __restrict__ statp) {
  const int t = threadIdx.x, lane = t & 63, w = t >> 6;
  const int bh = blockIdx.y, js = blockIdx.z;
  const int i0 = blockIdx.x * 64 + w * 16;
  const int li = lane & 15, lg = lane >> 4;
  const u16* Qh = qb + ((size_t)bh * 2048 + i0 + li) * 64;
  const u16* Kb = kb + (size_t)bh * 2048 * 64;
  const bfx8 q0 = *(const bfx8*)&Qh[lg * 8];
  const bfx8 q1 = *(const bfx8*)&Qh[32 + lg * 8];
  float m = -1e30f, l = 0.f;
  const int jbeg = js * 512, jend = jbeg + 512;
  for (int j0 = jbeg; j0 < jend; j0 += 32) {
    const u16* KhA = Kb + (size_t)(j0 + li) * 64;
    const u16* KhB = KhA + 16 * 64;
    bfx8 a0 = *(const bfx8*)&KhA[lg * 8];
    bfx8 a1 = *(const bfx8*)&KhA[32 + lg * 8];
    bfx8 b0 = *(const bfx8*)&KhB[lg * 8];
    bfx8 b1 = *(const bfx8*)&KhB[32 + lg * 8];
    __builtin_amdgcn_sched_barrier(0);
    f32x4 sa = {0.f, 0.f, 0.f, 0.f}, sb = {0.f, 0.f, 0.f, 0.f};
    sa = __builtin_amdgcn_mfma_f32_16x16x32_bf16(a0, q0, sa, 0, 0, 0);
    sa = __builtin_amdgcn_mfma_f32_16x16x32_bf16(a1, q1, sa, 0, 0, 0);
    sb = __builtin_amdgcn_mfma_f32_16x16x32_bf16(b0, q0, sb, 0, 0, 0);
    sb = __builtin_amdgcn_mfma_f32_16x16x32_bf16(b1, q1, sb, 0, 0, 0);
    float mt = fmaxf(fmaxf(fmaxf(sa[0], sa[1]), fmaxf(sa[2], sa[3])),
                     fmaxf(fmaxf(sb[0], sb[1]), fmaxf(sb[2], sb[3])));
    float mn = fmaxf(m, mt);
    float es = (fexp2(sa[0] - mn) + fexp2(sa[1] - mn)) + (fexp2(sa[2] - mn) + fexp2(sa[3] - mn))
             + (fexp2(sb[0] - mn) + fexp2(sb[1] - mn)) + (fexp2(sb[2] - mn) + fexp2(sb[3] - mn));
    l = fmaf(l, fexp2(m - mn), es);
    m = mn;
  }
  for (int off = 16; off < 64; off <<= 1) {
    float mo = __shfl_xor(m, off, 64);
    float lo = __shfl_xor(l, off, 64);
    float mn = fmaxf(m, mo);
    l = l * fexp2(m - mn) + lo * fexp2(mo - mn);
    m = mn;
  }
  if (lane < 16) statp[(size_t)js * 32768 + (size_t)bh * 2048 + i0 + li] = make_float2(m, l);
}

// ---------------- k3: kFused — QK^T + softmax + mix + LN + PV, S in LDS ----------------
// grid (32 i-tiles of 64, 2 b, 4 j-quarters), 512 thr = 8 waves, wave = head.
__global__ __launch_bounds__(512) void kFused(
    const u16* __restrict__ qb, const u16* __restrict__ kb,
    const u16* __restrict__ vtb, const float2* __restrict__ statp,
    const float* __restrict__ Wmix, const float* __restrict__ lng,
    const float* __restrict__ lnb, float* __restrict__ innerF) {
  __shared__ __align__(16) u16 Spk[64 * 512];     // 64KB  p bf16 [i][h][x]
  __shared__ __align__(16) u16 A2h[8 * 64 * 72];  // 72KB  A'' bf16 [g][i][x]
  __shared__ float stMs[64 * 8];                  // 2KB   M = m+log2(l) [i][h]
  const int t = threadIdx.x, lane = t & 63, w = t >> 6;
  const int li = lane & 15, lg = lane >> 4;
  const int ig = blockIdx.x * 64, b = blockIdx.y, j0 = blockIdx.z * 512;

  float wm_[8][8], lng_[8], lnb_[8];   // uniform -> SGPR
#pragma unroll
  for (int h = 0; h < 8; h++)
#pragma unroll
    for (int g = 0; g < 8; g++) wm_[h][g] = Wmix[h * 8 + g];
#pragma unroll
  for (int g = 0; g < 8; g++) { lng_[g] = lng[g]; lnb_[g] = lnb[g]; }

  // stats merge -> stMs[i][h]
  {
    const int i = t >> 3, h = t & 7;
    const size_t idx = ((size_t)(b * 8 + h)) * 2048 + ig + i;
    float m = -1e30f, l = 0.f;
#pragma unroll
    for (int z = 0; z < 4; z++) {
      const float2 a = statp[(size_t)z * 32768 + idx];
      const float mn = fmaxf(m, a.x);
      l = l * fexp2(m - mn) + a.y * fexp2(a.x - mn);
      m = mn;
    }
    stMs[i * 8 + h] = m + flog2(l);
  }

  // Q fragments for head w (held in regs for the whole block)
  bfx8 qf[4][2];
#pragma unroll
  for (int ii = 0; ii < 4; ii++)
#pragma unroll
    for (int ks = 0; ks < 2; ks++)
      qf[ii][ks] = *(const bfx8*)&qb[(((size_t)(b * 8 + w)) * 2048 + ig + ii * 16 + li) * 64
                                     + ks * 32 + lg * 8];
  __syncthreads();
  float stMp[4];
#pragma unroll
  for (int ii = 0; ii < 4; ii++) stMp[ii] = stMs[(ii * 16 + li) * 8 + w];

  f32x4 pacc[4][4] = {};
  const int mixI = t >> 3, mixJ8 = (t & 7) * 8;   // mix-phase position base
  const int mixSwz = (mixI & 7) << 3;

  // K prologue: fragments for tile 0
  bfx8 kf[4][2];
#pragma unroll
  for (int ji = 0; ji < 4; ji++)
#pragma unroll
    for (int ks = 0; ks < 2; ks++)
      kf[ji][ks] = *(const bfx8*)&kb[(((size_t)(b * 8 + w)) * 2048 + j0 + ji * 16 + li) * 64
                                     + ks * 32 + lg * 8];

  for (int jt = j0; jt < j0 + 512; jt += 64) {
    // V prefetch (both halves issued at tile top; used only in PV)
    bfx8 vf0[4], vf1[4];
#pragma unroll
    for (int dt = 0; dt < 4; dt++) {
      vf0[dt] = *(const bfx8*)&vtb[(((size_t)(b * 8 + w)) * 64 + dt * 16 + li) * 2048
                                   + jt + lg * 8];
      vf1[dt] = *(const bfx8*)&vtb[(((size_t)(b * 8 + w)) * 64 + dt * 16 + li) * 2048
                                   + jt + 32 + lg * 8];
    }
    __builtin_amdgcn_sched_barrier(0);
    // QK^T + exp + pack to Spk. element: j = jt + ji*16 + lg*4 + r, i = ii*16 + li.
#pragma unroll
    for (int ii = 0; ii < 4; ii++) {
      f32x4 s[4] = {};
#pragma unroll
      for (int ji = 0; ji < 4; ji++) {
        s[ji] = __builtin_amdgcn_mfma_f32_16x16x32_bf16(kf[ji][0], qf[ii][0], s[ji], 0, 0, 0);
        s[ji] = __builtin_amdgcn_mfma_f32_16x16x32_bf16(kf[ji][1], qf[ii][1], s[ji], 0, 0, 0);
      }
      const int i = ii * 16 + li;
      const int swzI = (i & 7) << 3;
#pragma unroll
      for (int ji = 0; ji < 4; ji++) {
        const float p0 = fexp2(s[ji][0] - stMp[ii]);
        const float p1 = fexp2(s[ji][1] - stMp[ii]);
        const float p2 = fexp2(s[ji][2] - stMp[ii]);
        const float p3 = fexp2(s[ji][3] - stMp[ii]);
        const int x = (ji * 16 + lg * 4) ^ swzI;
        *(uint2*)&Spk[i * 512 + w * 64 + x] = make_uint2(cvtpk(p0, p1), cvtpk(p2, p3));
      }
    }
    // K prefetch for NEXT tile — latency hidden under mix (~1300 cy)
    {
      const int jn = (jt + 64 < j0 + 512) ? jt + 64 : j0;
#pragma unroll
      for (int ji = 0; ji < 4; ji++)
#pragma unroll
        for (int ks = 0; ks < 2; ks++)
          kf[ji][ks] = *(const bfx8*)&kb[(((size_t)(b * 8 + w)) * 2048 + jn + ji * 16 + li) * 64
                                         + ks * 32 + lg * 8];
      __builtin_amdgcn_sched_barrier(0);
    }
    __syncthreads();
    // MIX + LN: thread handles 8 positions (i = mixI, j = jt + mixJ8 + 0..7)
    {
      u32 ogw[8][4];
      float tmp[8];
#pragma unroll
      for (int hf = 0; hf < 2; hf++) {
        float p[8][4];
#pragma unroll
        for (int h = 0; h < 8; h++) {
          const int x4 = (mixJ8 + hf * 4) ^ mixSwz;
          const uint2 v = *(const uint2*)&Spk[mixI * 512 + h * 64 + x4];
          union { u32 u; float f; } c0, c1, c2, c3;
          c0.u = v.x << 16; c1.u = v.x & 0xffff0000u;
          c2.u = v.y << 16; c3.u = v.y & 0xffff0000u;
          p[h][0] = c0.f; p[h][1] = c1.f; p[h][2] = c2.f; p[h][3] = c3.f;
        }
#pragma unroll
        for (int e = 0; e < 4; e++) {
          float a_[8]; float sum = 0.f, sumsq = 0.f;
#pragma unroll
          for (int g = 0; g < 8; g++) {
            float acc = 0.f;
#pragma unroll
            for (int h = 0; h < 8; h++) acc = fmaf(p[h][e], wm_[h][g], acc);
            a_[g] = acc; sum += acc; sumsq = fmaf(acc, acc, sumsq);
          }
          const float mu = sum * 0.125f;
          const float var = fmaf(sumsq, 0.125f, -mu * mu);
          const float rs = rsqrtf(var + 1e-5f);
#pragma unroll
          for (int g = 0; g < 8; g++) {
            const float av = fmaf((a_[g] - mu) * rs, lng_[g], lnb_[g]);
            if (e & 1) ogw[g][hf * 2 + (e >> 1)] = cvtpk(tmp[g], av);
            else       tmp[g] = av;
          }
        }
      }
#pragma unroll
      for (int g = 0; g < 8; g++)
        *(uint4*)&A2h[g * 4608 + mixI * 72 + (mixJ8 ^ mixSwz)] =
            make_uint4(ogw[g][0], ogw[g][1], ogw[g][2], ogw[g][3]);
    }
    __syncthreads();
    // PV: head w; A = A''[i][j] from A2h, B = V (prefetched at tile top)
    __builtin_amdgcn_s_setprio(1);
#pragma unroll
    for (int iSub = 0; iSub < 4; iSub++) {
      const bfx8 af0 = *(const bfx8*)&A2h[w * 4608 + (iSub * 16 + li) * 72
                                          + ((lg * 8) ^ ((li & 7) << 3))];
#pragma unroll
      for (int dt = 0; dt < 4; dt++)
        pacc[iSub][dt] = __builtin_amdgcn_mfma_f32_16x16x32_bf16(af0, vf0[dt], pacc[iSub][dt], 0, 0, 0);
    }
#pragma unroll
    for (int iSub = 0; iSub < 4; iSub++) {
      const bfx8 af1 = *(const bfx8*)&A2h[w * 4608 + (iSub * 16 + li) * 72
                                          + ((32 + lg * 8) ^ ((li & 7) << 3))];
#pragma unroll
      for (int dt = 0; dt < 4; dt++)
        pacc[iSub][dt] = __builtin_amdgcn_mfma_f32_16x16x32_bf16(af1, vf1[dt], pacc[iSub][dt], 0, 0, 0);
    }
    __builtin_amdgcn_s_setprio(0);
    __syncthreads();
  }
  // epilogue: f32 atomic partials (4 j-quarter contributions per element)
#pragma unroll
  for (int iSub = 0; iSub < 4; iSub++)
#pragma unroll
    for (int dt = 0; dt < 4; dt++)
#pragma unroll
      for (int r = 0; r < 4; r++)
        atomicAdd(&innerF[((size_t)b * 2048 + ig + iSub * 16 + lg * 4 + r) * 512
                          + w * 64 + dt * 16 + li],
                  pacc[iSub][dt][r]);
}

// ---------------- k4: inner f32 -> bf16 ----------------
__global__ __launch_bounds__(256) void convertInner(
    const float* __restrict__ inF, u16* __restrict__ outB) {
  int e = (blockIdx.x * 256 + threadIdx.x) * 4;
  float4 v = *(const float4*)&inF[e];
  ushort4 o; o.x = f2bf(v.x); o.y = f2bf(v.y); o.z = f2bf(v.z); o.w = f2bf(v.w);
  *(ushort4*)&outB[e] = o;
}

// ---------------- k5: out = inner @ w_out^T + b_out (B stage-converted f32) ----------------
__global__ __launch_bounds__(256) void gemm_out(
    const u16* __restrict__ A, const float* __restrict__ B,
    float* __restrict__ outf, const float* __restrict__ bias) {
  __shared__ u16 As[128 * 32];
  __shared__ u16 Bs[128 * 32];
  const int t = threadIdx.x, lane = t & 63;
  const int wm = (t >> 6) >> 1, wn = (t >> 6) & 1;
  const int m0 = blockIdx.y * 128, n0 = blockIdx.x * 128;
  const int li = lane & 15, lg = lane >> 4;
  const int rowA = t >> 2, kb8 = (t & 3) * 8;
  f32x4 acc[4][4] = {};
  for (int k0 = 0; k0 < 512; k0 += 32) {
    __syncthreads();
    *(bfx8*)&As[rowA * 32 + kb8]        = *(const bfx8*)&A[(size_t)(m0 + rowA) * 512 + k0 + kb8];
    *(bfx8*)&As[(rowA + 64) * 32 + kb8] = *(const bfx8*)&A[(size_t)(m0 + rowA + 64) * 512 + k0 + kb8];
    *(uint4*)&Bs[rowA * 32 + kb8]        = pk8(&B[(size_t)(n0 + rowA) * 512 + k0 + kb8]);
    *(uint4*)&Bs[(rowA + 64) * 32 + kb8] = pk8(&B[(size_t)(n0 + rowA + 64) * 512 + k0 + kb8]);
    __syncthreads();
    bfx8 af[4], bf_[4];
#pragma unroll
    for (int mi = 0; mi < 4; mi++)
      af[mi] = *(const bfx8*)&As[(wm * 64 + mi * 16 + li) * 32 + lg * 8];
#pragma unroll
    for (int ni = 0; ni < 4; ni++)
      bf_[ni] = *(const bfx8*)&Bs[(wn * 64 + ni * 16 + li) * 32 + lg * 8];
#pragma unroll
    for (int mi = 0; mi < 4; mi++)
#pragma unroll
      for (int ni = 0; ni < 4; ni++)
        acc[mi][ni] = __builtin_amdgcn_mfma_f32_16x16x32_bf16(af[mi], bf_[ni], acc[mi][ni], 0, 0, 0);
  }
#pragma unroll
  for (int mi = 0; mi < 4; mi++) {
#pragma unroll
    for (int ni = 0; ni < 4; ni++) {
      const int nc  = n0 + wn * 64 + ni * 16 + li;
      const int mrb = m0 + wm * 64 + mi * 16 + lg * 4;
      const float bv = bias[nc];
#pragma unroll
      for (int r = 0; r < 4; r++)
        outf[(size_t)(mrb + r) * 512 + nc] = acc[mi][ni][r] + bv;
    }
  }
}

// ---------------- host ----------------
extern "C" void kernel_launch(void* const* d_in, const int* in_sizes, int n_in,
                              void* d_out, int out_size, void* d_ws, size_t ws_size,
                              hipStream_t stream) {
  const float* x      = (const float*)d_in[0];
  const float* w_qkv  = (const float*)d_in[1];
  const float* reattn = (const float*)d_in[2];
  const float* ln_g   = (const float*)d_in[3];
  const float* ln_b   = (const float*)d_in[4];
  const float* w_out  = (const float*)d_in[5];
  const float* b_out  = (const float*)d_in[6];
  float* out = (float*)d_out;
  char* ws = (char*)d_ws;
  // ws layout (bytes), ~21 MB (proven budget):
  //  [0, 8388608)  : innerF f32 (zeroed after gemm_qkv)
  //  innerB bf16 reuses qbf region after kFused.
  float*  innerF= (float*)(ws + 0);
  u16*    qbf   = (u16*)(ws + 8388608);    // [2,8,2048,64] bf16 (scaled)
  u16*    kbf   = (u16*)(ws + 12582912);   // [2,8,2048,64] bf16
  u16*    vtb   = (u16*)(ws + 16777216);   // [2,8,64,2048] bf16
  float2* statp = (float2*)(ws + 20971520);// [4][2,8,2048] raw (m, l) partials
  u16*    innerB= (u16*)(ws + 8388608);    // reuses qbf after kFused

  gemm_qkv<<<dim3(12, 32), 256, 0, stream>>>(x, w_qkv, qbf, kbf, vtb);
  hipMemsetAsync(innerF, 0, 8388608, stream);
  passA<<<dim3(32, 16, 4), 256, 0, stream>>>(qbf, kbf, statp);
  kFused<<<dim3(32, 2, 4), 512, 0, stream>>>(qbf, kbf, vtb, statp, reattn, ln_g, ln_b, innerF);
  convertInner<<<2048, 256, 0, stream>>>(innerF, innerB);
  gemm_out<<<dim3(4, 32), 256, 0, stream>>>(innerB, w_out, out, b_out);
}

// Round 17
// 191.396 us; speedup vs baseline: 1.5242x; 1.0330x over previous
//
#include <hip/hip_runtime.h>
#include <hip/hip_bf16.h>

// DeepViT re-attention — fused S-in-LDS pipeline, v3.
//  k1 gemm_qkv: qkv = x @ w_qkv^T, f32 stage-convert, XCD-swizzled grid
//  (memset)   : zero innerF f32 accumulator
//  k2 passA   : softmax stats (m, l), j-split x4, XCD-swizzled grid
//  k3 kFused  : per 64-j tile: QK^T -> p bf16 -> Spk; mix+LN -> A2h; PV.
//               T14: V(t)+K(t+1) issued AFTER barrier1 so they drain at
//               barrier2 (hidden under mix ~1600cy) instead of barrier1.
//               uint4 Spk reads in mix. f32 atomicAdd partials.
//  k4 gemm_out: out = innerF(f32, staged-convert) @ w_out^T + b_out
//               (convertInner kernel eliminated)

typedef __attribute__((ext_vector_type(8))) short bfx8;
typedef __attribute__((ext_vector_type(4))) float f32x4;
typedef unsigned short u16;
typedef unsigned int u32;

#define QSCALE 0.18033688011112042f  /* (1/8) * log2(e) */

static __device__ inline u16 f2bf(float f) {
  union { float f; unsigned u; } cv; cv.f = f;
  unsigned u = cv.u;
  u += 0x7fffu + ((u >> 16) & 1u);   // RNE
  return (u16)(u >> 16);
}
static __device__ inline u32 cvtpk(float lo, float hi) {  // {bf16(lo), bf16(hi)}
  u32 d; asm("v_cvt_pk_bf16_f32 %0, %1, %2" : "=v"(d) : "v"(lo), "v"(hi)); return d;
}
static __device__ inline float fexp2(float x) {
  float r; asm("v_exp_f32 %0, %1" : "=v"(r) : "v"(x)); return r;
}
static __device__ inline float flog2(float x) {
  float r; asm("v_log_f32 %0, %1" : "=v"(r) : "v"(x)); return r;
}
static __device__ inline uint4 pk8(const float* p) {  // 8 f32 -> 8 bf16 (uint4)
  float4 a = *(const float4*)p, b = *(const float4*)(p + 4);
  return make_uint4(cvtpk(a.x, a.y), cvtpk(a.z, a.w), cvtpk(b.x, b.y), cvtpk(b.z, b.w));
}

// ---------------- k1: GEMM C = A @ B^T with f32->bf16 stage-convert ----------------
// grid 384 linear; XCD swizzle chunk=48 (384%8==0): same-row-panel blocks
// cluster on one XCD -> A panel fetched ~4x instead of ~32x.
__global__ __launch_bounds__(256) void gemm_qkv(
    const float* __restrict__ A, const float* __restrict__ B,
    u16* __restrict__ qb, u16* __restrict__ kb, u16* __restrict__ vtb) {
  __shared__ u16 As[128 * 32];
  __shared__ u16 Bs[128 * 32];
  const int bid = blockIdx.x;
  const int swzb = (bid & 7) * 48 + (bid >> 3);
  const int n0 = (swzb % 12) * 128, m0 = (swzb / 12) * 128;
  const int t = threadIdx.x, lane = t & 63;
  const int wm = (t >> 6) >> 1, wn = (t >> 6) & 1;
  const int li = lane & 15, lg = lane >> 4;
  const int rowA = t >> 2, kb8 = (t & 3) * 8;
  f32x4 acc[4][4] = {};
  for (int k0 = 0; k0 < 512; k0 += 32) {
    __syncthreads();
    *(uint4*)&As[rowA * 32 + kb8]        = pk8(&A[(size_t)(m0 + rowA) * 512 + k0 + kb8]);
    *(uint4*)&As[(rowA + 64) * 32 + kb8] = pk8(&A[(size_t)(m0 + rowA + 64) * 512 + k0 + kb8]);
    *(uint4*)&Bs[rowA * 32 + kb8]        = pk8(&B[(size_t)(n0 + rowA) * 512 + k0 + kb8]);
    *(uint4*)&Bs[(rowA + 64) * 32 + kb8] = pk8(&B[(size_t)(n0 + rowA + 64) * 512 + k0 + kb8]);
    __syncthreads();
    bfx8 af[4], bf_[4];
#pragma unroll
    for (int mi = 0; mi < 4; mi++)
      af[mi] = *(const bfx8*)&As[(wm * 64 + mi * 16 + li) * 32 + lg * 8];
#pragma unroll
    for (int ni = 0; ni < 4; ni++)
      bf_[ni] = *(const bfx8*)&Bs[(wn * 64 + ni * 16 + li) * 32 + lg * 8];
#pragma unroll
    for (int mi = 0; mi < 4; mi++)
#pragma unroll
      for (int ni = 0; ni < 4; ni++)
        acc[mi][ni] = __builtin_amdgcn_mfma_f32_16x16x32_bf16(af[mi], bf_[ni], acc[mi][ni], 0, 0, 0);
  }
#pragma unroll
  for (int mi = 0; mi < 4; mi++) {
#pragma unroll
    for (int ni = 0; ni < 4; ni++) {
      const int nc  = n0 + wn * 64 + ni * 16 + li;
      const int mrb = m0 + wm * 64 + mi * 16 + lg * 4;
      const int part = nc >> 9, within = nc & 511;
      const int h = within >> 6, d = within & 63;
      const int bb = mrb >> 11, ii = mrb & 2047;
      if (part == 0) {
#pragma unroll
        for (int r = 0; r < 4; r++)
          qb[(((size_t)bb * 8 + h) * 2048 + ii + r) * 64 + d] = f2bf(acc[mi][ni][r] * QSCALE);
      } else if (part == 1) {
#pragma unroll
        for (int r = 0; r < 4; r++)
          kb[(((size_t)bb * 8 + h) * 2048 + ii + r) * 64 + d] = f2bf(acc[mi][ni][r]);
      } else {
        ushort4 u;
        u.x = f2bf(acc[mi][ni][0]); u.y = f2bf(acc[mi][ni][1]);
        u.z = f2bf(acc[mi][ni][2]); u.w = f2bf(acc[mi][ni][3]);
        *(ushort4*)&vtb[(((size_t)bb * 8 + h) * 64 + d) * 2048 + ii] = u;
      }
    }
  }
}

// ---------------- k2: softmax stats (m, l), j-split x4, XCD-swizzled ----------------
// grid 2048 linear; chunk=256: same-(bh,js) K-slab blocks cluster per XCD.
__global__ __launch_bounds__(256) void passA(
    const u16* __restrict__ qb, const u16* __restrict__ kb,
    float2* __restrict__ statp) {
  const int bid = blockIdx.x;
  const int swzb = (bid & 7) * 256 + (bid >> 3);
  const int bx = swzb & 31, bh = (swzb >> 5) & 15, js = swzb >> 9;
  const int t = threadIdx.x, lane = t & 63, w = t >> 6;
  const int i0 = bx * 64 + w * 16;
  const int li = lane & 15, lg = lane >> 4;
  const u16* Qh = qb + ((size_t)bh * 2048 + i0 + li) * 64;
  const u16* Kb = kb + (size_t)bh * 2048 * 64;
  const bfx8 q0 = *(const bfx8*)&Qh[lg * 8];
  const bfx8 q1 = *(const bfx8*)&Qh[32 + lg * 8];
  float m = -1e30f, l = 0.f;
  const int jbeg = js * 512, jend = jbeg + 512;
  for (int j0 = jbeg; j0 < jend; j0 += 32) {
    const u16* KhA = Kb + (size_t)(j0 + li) * 64;
    const u16* KhB = KhA + 16 * 64;
    bfx8 a0 = *(const bfx8*)&KhA[lg * 8];
    bfx8 a1 = *(const bfx8*)&KhA[32 + lg * 8];
    bfx8 b0 = *(const bfx8*)&KhB[lg * 8];
    bfx8 b1 = *(const bfx8*)&KhB[32 + lg * 8];
    __builtin_amdgcn_sched_barrier(0);
    f32x4 sa = {0.f, 0.f, 0.f, 0.f}, sb = {0.f, 0.f, 0.f, 0.f};
    sa = __builtin_amdgcn_mfma_f32_16x16x32_bf16(a0, q0, sa, 0, 0, 0);
    sa = __builtin_amdgcn_mfma_f32_16x16x32_bf16(a1, q1, sa, 0, 0, 0);
    sb = __builtin_amdgcn_mfma_f32_16x16x32_bf16(b0, q0, sb, 0, 0, 0);
    sb = __builtin_amdgcn_mfma_f32_16x16x32_bf16(b1, q1, sb, 0, 0, 0);
    float mt = fmaxf(fmaxf(fmaxf(sa[0], sa[1]), fmaxf(sa[2], sa[3])),
                     fmaxf(fmaxf(sb[0], sb[1]), fmaxf(sb[2], sb[3])));
    float mn = fmaxf(m, mt);
    float es = (fexp2(sa[0] - mn) + fexp2(sa[1] - mn)) + (fexp2(sa[2] - mn) + fexp2(sa[3] - mn))
             + (fexp2(sb[0] - mn) + fexp2(sb[1] - mn)) + (fexp2(sb[2] - mn) + fexp2(sb[3] - mn));
    l = fmaf(l, fexp2(m - mn), es);
    m = mn;
  }
  for (int off = 16; off < 64; off <<= 1) {
    float mo = __shfl_xor(m, off, 64);
    float lo = __shfl_xor(l, off, 64);
    float mn = fmaxf(m, mo);
    l = l * fexp2(m - mn) + lo * fexp2(mo - mn);
    m = mn;
  }
  if (lane < 16) statp[(size_t)js * 32768 + (size_t)bh * 2048 + i0 + li] = make_float2(m, l);
}

// ---------------- k3: kFused — QK^T + softmax + mix + LN + PV, S in LDS ----------------
// grid (32 i-tiles of 64, 2 b, 4 j-quarters), 512 thr = 8 waves, wave = head.
__global__ __launch_bounds__(512) void kFused(
    const u16* __restrict__ qb, const u16* __restrict__ kb,
    const u16* __restrict__ vtb, const float2* __restrict__ statp,
    const float* __restrict__ Wmix, const float* __restrict__ lng,
    const float* __restrict__ lnb, float* __restrict__ innerF) {
  __shared__ __align__(16) u16 Spk[64 * 512];     // 64KB  p bf16 [i][h][x]
  __shared__ __align__(16) u16 A2h[8 * 64 * 72];  // 72KB  A'' bf16 [g][i][x]
  __shared__ float stMs[64 * 8];                  // 2KB   M = m+log2(l) [i][h]
  const int t = threadIdx.x, lane = t & 63, w = t >> 6;
  const int li = lane & 15, lg = lane >> 4;
  const int ig = blockIdx.x * 64, b = blockIdx.y, j0 = blockIdx.z * 512;

  float wm_[8][8], lng_[8], lnb_[8];   // uniform -> SGPR
#pragma unroll
  for (int h = 0; h < 8; h++)
#pragma unroll
    for (int g = 0; g < 8; g++) wm_[h][g] = Wmix[h * 8 + g];
#pragma unroll
  for (int g = 0; g < 8; g++) { lng_[g] = lng[g]; lnb_[g] = lnb[g]; }

  // stats merge -> stMs[i][h]
  {
    const int i = t >> 3, h = t & 7;
    const size_t idx = ((size_t)(b * 8 + h)) * 2048 + ig + i;
    float m = -1e30f, l = 0.f;
#pragma unroll
    for (int z = 0; z < 4; z++) {
      const float2 a = statp[(size_t)z * 32768 + idx];
      const float mn = fmaxf(m, a.x);
      l = l * fexp2(m - mn) + a.y * fexp2(a.x - mn);
      m = mn;
    }
    stMs[i * 8 + h] = m + flog2(l);
  }

  // Q fragments for head w (held in regs for the whole block)
  bfx8 qf[4][2];
#pragma unroll
  for (int ii = 0; ii < 4; ii++)
#pragma unroll
    for (int ks = 0; ks < 2; ks++)
      qf[ii][ks] = *(const bfx8*)&qb[(((size_t)(b * 8 + w)) * 2048 + ig + ii * 16 + li) * 64
                                     + ks * 32 + lg * 8];
  __syncthreads();
  float stMp[4];
#pragma unroll
  for (int ii = 0; ii < 4; ii++) stMp[ii] = stMs[(ii * 16 + li) * 8 + w];

  f32x4 pacc[4][4] = {};
  const int mixI = t >> 3, mixJ8 = (t & 7) * 8;   // mix-phase position base
  const int mixSwz = (mixI & 7) << 3;

  // K prologue: fragments for tile 0
  bfx8 kf[4][2];
#pragma unroll
  for (int ji = 0; ji < 4; ji++)
#pragma unroll
    for (int ks = 0; ks < 2; ks++)
      kf[ji][ks] = *(const bfx8*)&kb[(((size_t)(b * 8 + w)) * 2048 + j0 + ji * 16 + li) * 64
                                     + ks * 32 + lg * 8];

  for (int jt = j0; jt < j0 + 512; jt += 64) {
    // QK^T + exp + pack to Spk. element: j = jt + ji*16 + lg*4 + r, i = ii*16 + li.
#pragma unroll
    for (int ii = 0; ii < 4; ii++) {
      f32x4 s[4] = {};
#pragma unroll
      for (int ji = 0; ji < 4; ji++) {
        s[ji] = __builtin_amdgcn_mfma_f32_16x16x32_bf16(kf[ji][0], qf[ii][0], s[ji], 0, 0, 0);
        s[ji] = __builtin_amdgcn_mfma_f32_16x16x32_bf16(kf[ji][1], qf[ii][1], s[ji], 0, 0, 0);
      }
      const int i = ii * 16 + li;
      const int swzI = (i & 7) << 3;
#pragma unroll
      for (int ji = 0; ji < 4; ji++) {
        const float p0 = fexp2(s[ji][0] - stMp[ii]);
        const float p1 = fexp2(s[ji][1] - stMp[ii]);
        const float p2 = fexp2(s[ji][2] - stMp[ii]);
        const float p3 = fexp2(s[ji][3] - stMp[ii]);
        const int x = (ji * 16 + lg * 4) ^ swzI;
        *(uint2*)&Spk[i * 512 + w * 64 + x] = make_uint2(cvtpk(p0, p1), cvtpk(p2, p3));
      }
    }
    __syncthreads();   // barrier1: Spk ready (drains Spk writes)
    // T14: V(current) + K(next) issued HERE -> drained at barrier2, hidden by mix
    bfx8 vf0[4], vf1[4];
#pragma unroll
    for (int dt = 0; dt < 4; dt++) {
      vf0[dt] = *(const bfx8*)&vtb[(((size_t)(b * 8 + w)) * 64 + dt * 16 + li) * 2048
                                   + jt + lg * 8];
      vf1[dt] = *(const bfx8*)&vtb[(((size_t)(b * 8 + w)) * 64 + dt * 16 + li) * 2048
                                   + jt + 32 + lg * 8];
    }
    {
      const int jn = (jt + 64 < j0 + 512) ? jt + 64 : j0;
#pragma unroll
      for (int ji = 0; ji < 4; ji++)
#pragma unroll
        for (int ks = 0; ks < 2; ks++)
          kf[ji][ks] = *(const bfx8*)&kb[(((size_t)(b * 8 + w)) * 2048 + jn + ji * 16 + li) * 64
                                         + ks * 32 + lg * 8];
    }
    __builtin_amdgcn_sched_barrier(0);
    // MIX + LN: thread handles 8 positions (i = mixI, j = jt + mixJ8 + 0..7)
    {
      uint4 sv[8];
#pragma unroll
      for (int h = 0; h < 8; h++)
        sv[h] = *(const uint4*)&Spk[mixI * 512 + h * 64 + (mixJ8 ^ mixSwz)];
      u32 ogw[8][4];
      float tmp[8];
#pragma unroll
      for (int hf = 0; hf < 2; hf++) {
        float p[8][4];
#pragma unroll
        for (int h = 0; h < 8; h++) {
          const u32 va = hf ? sv[h].z : sv[h].x;
          const u32 vb = hf ? sv[h].w : sv[h].y;
          union { u32 u; float f; } c0, c1, c2, c3;
          c0.u = va << 16; c1.u = va & 0xffff0000u;
          c2.u = vb << 16; c3.u = vb & 0xffff0000u;
          p[h][0] = c0.f; p[h][1] = c1.f; p[h][2] = c2.f; p[h][3] = c3.f;
        }
#pragma unroll
        for (int e = 0; e < 4; e++) {
          float a_[8]; float sum = 0.f, sumsq = 0.f;
#pragma unroll
          for (int g = 0; g < 8; g++) {
            float acc = 0.f;
#pragma unroll
            for (int h = 0; h < 8; h++) acc = fmaf(p[h][e], wm_[h][g], acc);
            a_[g] = acc; sum += acc; sumsq = fmaf(acc, acc, sumsq);
          }
          const float mu = sum * 0.125f;
          const float var = fmaf(sumsq, 0.125f, -mu * mu);
          const float rs = rsqrtf(var + 1e-5f);
#pragma unroll
          for (int g = 0; g < 8; g++) {
            const float av = fmaf((a_[g] - mu) * rs, lng_[g], lnb_[g]);
            if (e & 1) ogw[g][hf * 2 + (e >> 1)] = cvtpk(tmp[g], av);
            else       tmp[g] = av;
          }
        }
      }
#pragma unroll
      for (int g = 0; g < 8; g++)
        *(uint4*)&A2h[g * 4608 + mixI * 72 + (mixJ8 ^ mixSwz)] =
            make_uint4(ogw[g][0], ogw[g][1], ogw[g][2], ogw[g][3]);
    }
    __syncthreads();   // barrier2: A2h ready; drains V/K prefetch (hidden by mix)
    // PV: head w; A = A''[i][j] from A2h, B = V (prefetched under mix)
    __builtin_amdgcn_s_setprio(1);
#pragma unroll
    for (int iSub = 0; iSub < 4; iSub++) {
      const bfx8 af0 = *(const bfx8*)&A2h[w * 4608 + (iSub * 16 + li) * 72
                                          + ((lg * 8) ^ ((li & 7) << 3))];
#pragma unroll
      for (int dt = 0; dt < 4; dt++)
        pacc[iSub][dt] = __builtin_amdgcn_mfma_f32_16x16x32_bf16(af0, vf0[dt], pacc[iSub][dt], 0, 0, 0);
    }
#pragma unroll
    for (int iSub = 0; iSub < 4; iSub++) {
      const bfx8 af1 = *(const bfx8*)&A2h[w * 4608 + (iSub * 16 + li) * 72
                                          + ((32 + lg * 8) ^ ((li & 7) << 3))];
#pragma unroll
      for (int dt = 0; dt < 4; dt++)
        pacc[iSub][dt] = __builtin_amdgcn_mfma_f32_16x16x32_bf16(af1, vf1[dt], pacc[iSub][dt], 0, 0, 0);
    }
    __builtin_amdgcn_s_setprio(0);
    __syncthreads();
  }
  // epilogue: f32 atomic partials (4 j-quarter contributions per element)
#pragma unroll
  for (int iSub = 0; iSub < 4; iSub++)
#pragma unroll
    for (int dt = 0; dt < 4; dt++)
#pragma unroll
      for (int r = 0; r < 4; r++)
        atomicAdd(&innerF[((size_t)b * 2048 + ig + iSub * 16 + lg * 4 + r) * 512
                          + w * 64 + dt * 16 + li],
                  pacc[iSub][dt][r]);
}

// ---------------- k4: out = innerF(f32) @ w_out^T + b_out, fused convert ----------------
__global__ __launch_bounds__(256) void gemm_out(
    const float* __restrict__ A, const float* __restrict__ B,
    float* __restrict__ outf, const float* __restrict__ bias) {
  __shared__ u16 As[128 * 32];
  __shared__ u16 Bs[128 * 32];
  const int bid = blockIdx.x;
  const int swzb = (bid & 7) * 16 + (bid >> 3);
  const int n0 = (swzb & 3) * 128, m0 = (swzb >> 2) * 128;
  const int t = threadIdx.x, lane = t & 63;
  const int wm = (t >> 6) >> 1, wn = (t >> 6) & 1;
  const int li = lane & 15, lg = lane >> 4;
  const int rowA = t >> 2, kb8 = (t & 3) * 8;
  f32x4 acc[4][4] = {};
  for (int k0 = 0; k0 < 512; k0 += 32) {
    __syncthreads();
    *(uint4*)&As[rowA * 32 + kb8]        = pk8(&A[(size_t)(m0 + rowA) * 512 + k0 + kb8]);
    *(uint4*)&As[(rowA + 64) * 32 + kb8] = pk8(&A[(size_t)(m0 + rowA + 64) * 512 + k0 + kb8]);
    *(uint4*)&Bs[rowA * 32 + kb8]        = pk8(&B[(size_t)(n0 + rowA) * 512 + k0 + kb8]);
    *(uint4*)&Bs[(rowA + 64) * 32 + kb8] = pk8(&B[(size_t)(n0 + rowA + 64) * 512 + k0 + kb8]);
    __syncthreads();
    bfx8 af[4], bf_[4];
#pragma unroll
    for (int mi = 0; mi < 4; mi++)
      af[mi] = *(const bfx8*)&As[(wm * 64 + mi * 16 + li) * 32 + lg * 8];
#pragma unroll
    for (int ni = 0; ni < 4; ni++)
      bf_[ni] = *(const bfx8*)&Bs[(wn * 64 + ni * 16 + li) * 32 + lg * 8];
#pragma unroll
    for (int mi = 0; mi < 4; mi++)
#pragma unroll
      for (int ni = 0; ni < 4; ni++)
        acc[mi][ni] = __builtin_amdgcn_mfma_f32_16x16x32_bf16(af[mi], bf_[ni], acc[mi][ni], 0, 0, 0);
  }
#pragma unroll
  for (int mi = 0; mi < 4; mi++) {
#pragma unroll
    for (int ni = 0; ni < 4; ni++) {
      const int nc  = n0 + wn * 64 + ni * 16 + li;
      const int mrb = m0 + wm * 64 + mi * 16 + lg * 4;
      const float bv = bias[nc];
#pragma unroll
      for (int r = 0; r < 4; r++)
        outf[(size_t)(mrb + r) * 512 + nc] = acc[mi][ni][r] + bv;
    }
  }
}

// ---------------- host ----------------
extern "C" void kernel_launch(void* const* d_in, const int* in_sizes, int n_in,
                              void* d_out, int out_size, void* d_ws, size_t ws_size,
                              hipStream_t stream) {
  const float* x      = (const float*)d_in[0];
  const float* w_qkv  = (const float*)d_in[1];
  const float* reattn = (const float*)d_in[2];
  const float* ln_g   = (const float*)d_in[3];
  const float* ln_b   = (const float*)d_in[4];
  const float* w_out  = (const float*)d_in[5];
  const float* b_out  = (const float*)d_in[6];
  float* out = (float*)d_out;
  char* ws = (char*)d_ws;
  // ws layout (bytes), ~21 MB (proven budget):
  //  [0, 8388608)  : innerF f32 (zeroed after gemm_qkv; read f32 by gemm_out)
  float*  innerF= (float*)(ws + 0);
  u16*    qbf   = (u16*)(ws + 8388608);    // [2,8,2048,64] bf16 (scaled)
  u16*    kbf   = (u16*)(ws + 12582912);   // [2,8,2048,64] bf16
  u16*    vtb   = (u16*)(ws + 16777216);   // [2,8,64,2048] bf16
  float2* statp = (float2*)(ws + 20971520);// [4][2,8,2048] raw (m, l) partials

  gemm_qkv<<<384, 256, 0, stream>>>(x, w_qkv, qbf, kbf, vtb);
  hipMemsetAsync(innerF, 0, 8388608, stream);
  passA<<<2048, 256, 0, stream>>>(qbf, kbf, statp);
  kFused<<<dim3(32, 2, 4), 512, 0, stream>>>(qbf, kbf, vtb, statp, reattn, ln_g, ln_b, innerF);
  gemm_out<<<128, 256, 0, stream>>>(innerF, w_out, out, b_out);
}

// Round 18
// 185.611 us; speedup vs baseline: 1.5717x; 1.0312x over previous
//
#include <hip/hip_runtime.h>
#include <hip/hip_bf16.h>

// DeepViT re-attention — fused S-in-LDS pipeline, v4.
//  k1 gemm_qkv: qkv = x @ w_qkv^T, BM=64 tile (768 blocks = 3/CU exact),
//               f32 stage-convert, XCD swizzle, fused innerF zeroing
//  k2 passA   : softmax stats (m, l), j-split x8 (4096 blocks), XCD swizzle
//  k3 kFused  : per 64-j tile: QK^T -> p bf16 -> Spk; mix+LN -> A2h; PV.
//               2 barriers/tile (barrier3 elided: PV reads A2h, next QK^T
//               writes Spk — disjoint; mix(t+1) A2h writes fenced by
//               barrier1(t+1)). T14 V/K prefetch drains at barrier2.
//  k4 gemm_out: out = innerF(f32 staged) @ w_out^T + b_out, BM=64 (256 blocks)

typedef __attribute__((ext_vector_type(8))) short bfx8;
typedef __attribute__((ext_vector_type(4))) float f32x4;
typedef unsigned short u16;
typedef unsigned int u32;

#define QSCALE 0.18033688011112042f  /* (1/8) * log2(e) */

static __device__ inline u16 f2bf(float f) {
  union { float f; unsigned u; } cv; cv.f = f;
  unsigned u = cv.u;
  u += 0x7fffu + ((u >> 16) & 1u);   // RNE
  return (u16)(u >> 16);
}
static __device__ inline u32 cvtpk(float lo, float hi) {  // {bf16(lo), bf16(hi)}
  u32 d; asm("v_cvt_pk_bf16_f32 %0, %1, %2" : "=v"(d) : "v"(lo), "v"(hi)); return d;
}
static __device__ inline float fexp2(float x) {
  float r; asm("v_exp_f32 %0, %1" : "=v"(r) : "v"(x)); return r;
}
static __device__ inline float flog2(float x) {
  float r; asm("v_log_f32 %0, %1" : "=v"(r) : "v"(x)); return r;
}
static __device__ inline uint4 pk8(const float* p) {  // 8 f32 -> 8 bf16 (uint4)
  float4 a = *(const float4*)p, b = *(const float4*)(p + 4);
  return make_uint4(cvtpk(a.x, a.y), cvtpk(a.z, a.w), cvtpk(b.x, b.y), cvtpk(b.z, b.w));
}

// ---------------- k1: GEMM C = x @ w_qkv^T, BM=64, fused innerF zero ----------------
// grid 768 linear; swizzle chunk 96; wave w owns cols w*32 (ni 0..1), all 4 mi.
__global__ __launch_bounds__(256) void gemm_qkv(
    const float* __restrict__ A, const float* __restrict__ B,
    u16* __restrict__ qb, u16* __restrict__ kb, u16* __restrict__ vtb,
    float4* __restrict__ zeroF) {
  __shared__ u16 As[64 * 32];
  __shared__ u16 Bs[128 * 32];
  const int bid = blockIdx.x, t = threadIdx.x;
  // fused zeroing of innerF (524288 float4s, 196608 threads)
  for (int e = bid * 256 + t; e < 524288; e += 196608)
    zeroF[e] = make_float4(0.f, 0.f, 0.f, 0.f);
  const int swzb = (bid & 7) * 96 + (bid >> 3);
  const int m0 = (swzb / 12) * 64, n0 = (swzb % 12) * 128;
  const int lane = t & 63, w = t >> 6;
  const int li = lane & 15, lg = lane >> 4;
  const int rowA = t >> 2, kb8 = (t & 3) * 8;
  f32x4 acc[4][2] = {};
  for (int k0 = 0; k0 < 512; k0 += 32) {
    __syncthreads();
    *(uint4*)&As[rowA * 32 + kb8]        = pk8(&A[(size_t)(m0 + rowA) * 512 + k0 + kb8]);
    *(uint4*)&Bs[rowA * 32 + kb8]        = pk8(&B[(size_t)(n0 + rowA) * 512 + k0 + kb8]);
    *(uint4*)&Bs[(rowA + 64) * 32 + kb8] = pk8(&B[(size_t)(n0 + rowA + 64) * 512 + k0 + kb8]);
    __syncthreads();
    bfx8 af[4], bf_[2];
#pragma unroll
    for (int mi = 0; mi < 4; mi++)
      af[mi] = *(const bfx8*)&As[(mi * 16 + li) * 32 + lg * 8];
#pragma unroll
    for (int ni = 0; ni < 2; ni++)
      bf_[ni] = *(const bfx8*)&Bs[(w * 32 + ni * 16 + li) * 32 + lg * 8];
#pragma unroll
    for (int mi = 0; mi < 4; mi++)
#pragma unroll
      for (int ni = 0; ni < 2; ni++)
        acc[mi][ni] = __builtin_amdgcn_mfma_f32_16x16x32_bf16(af[mi], bf_[ni], acc[mi][ni], 0, 0, 0);
  }
#pragma unroll
  for (int mi = 0; mi < 4; mi++) {
#pragma unroll
    for (int ni = 0; ni < 2; ni++) {
      const int nc  = n0 + w * 32 + ni * 16 + li;
      const int mrb = m0 + mi * 16 + lg * 4;
      const int part = nc >> 9, within = nc & 511;
      const int h = within >> 6, d = within & 63;
      const int bb = mrb >> 11, ii = mrb & 2047;
      if (part == 0) {
#pragma unroll
        for (int r = 0; r < 4; r++)
          qb[(((size_t)bb * 8 + h) * 2048 + ii + r) * 64 + d] = f2bf(acc[mi][ni][r] * QSCALE);
      } else if (part == 1) {
#pragma unroll
        for (int r = 0; r < 4; r++)
          kb[(((size_t)bb * 8 + h) * 2048 + ii + r) * 64 + d] = f2bf(acc[mi][ni][r]);
      } else {
        ushort4 u;
        u.x = f2bf(acc[mi][ni][0]); u.y = f2bf(acc[mi][ni][1]);
        u.z = f2bf(acc[mi][ni][2]); u.w = f2bf(acc[mi][ni][3]);
        *(ushort4*)&vtb[(((size_t)bb * 8 + h) * 64 + d) * 2048 + ii] = u;
      }
    }
  }
}

// ---------------- k2: softmax stats (m, l), j-split x8, XCD-swizzled ----------------
// grid 4096 linear; chunk=512.
__global__ __launch_bounds__(256) void passA(
    const u16* __restrict__ qb, const u16* __restrict__ kb,
    float2* __restrict__ statp) {
  const int bid = blockIdx.x;
  const int swzb = (bid & 7) * 512 + (bid >> 3);
  const int bx = swzb & 31, bh = (swzb >> 5) & 15, js = swzb >> 9;  // js 0..7
  const int t = threadIdx.x, lane = t & 63, w = t >> 6;
  const int i0 = bx * 64 + w * 16;
  const int li = lane & 15, lg = lane >> 4;
  const u16* Qh = qb + ((size_t)bh * 2048 + i0 + li) * 64;
  const u16* Kb = kb + (size_t)bh * 2048 * 64;
  const bfx8 q0 = *(const bfx8*)&Qh[lg * 8];
  const bfx8 q1 = *(const bfx8*)&Qh[32 + lg * 8];
  float m = -1e30f, l = 0.f;
  const int jbeg = js * 256, jend = jbeg + 256;
  for (int j0 = jbeg; j0 < jend; j0 += 32) {
    const u16* KhA = Kb + (size_t)(j0 + li) * 64;
    const u16* KhB = KhA + 16 * 64;
    bfx8 a0 = *(const bfx8*)&KhA[lg * 8];
    bfx8 a1 = *(const bfx8*)&KhA[32 + lg * 8];
    bfx8 b0 = *(const bfx8*)&KhB[lg * 8];
    bfx8 b1 = *(const bfx8*)&KhB[32 + lg * 8];
    __builtin_amdgcn_sched_barrier(0);
    f32x4 sa = {0.f, 0.f, 0.f, 0.f}, sb = {0.f, 0.f, 0.f, 0.f};
    sa = __builtin_amdgcn_mfma_f32_16x16x32_bf16(a0, q0, sa, 0, 0, 0);
    sa = __builtin_amdgcn_mfma_f32_16x16x32_bf16(a1, q1, sa, 0, 0, 0);
    sb = __builtin_amdgcn_mfma_f32_16x16x32_bf16(b0, q0, sb, 0, 0, 0);
    sb = __builtin_amdgcn_mfma_f32_16x16x32_bf16(b1, q1, sb, 0, 0, 0);
    float mt = fmaxf(fmaxf(fmaxf(sa[0], sa[1]), fmaxf(sa[2], sa[3])),
                     fmaxf(fmaxf(sb[0], sb[1]), fmaxf(sb[2], sb[3])));
    float mn = fmaxf(m, mt);
    float es = (fexp2(sa[0] - mn) + fexp2(sa[1] - mn)) + (fexp2(sa[2] - mn) + fexp2(sa[3] - mn))
             + (fexp2(sb[0] - mn) + fexp2(sb[1] - mn)) + (fexp2(sb[2] - mn) + fexp2(sb[3] - mn));
    l = fmaf(l, fexp2(m - mn), es);
    m = mn;
  }
  for (int off = 16; off < 64; off <<= 1) {
    float mo = __shfl_xor(m, off, 64);
    float lo = __shfl_xor(l, off, 64);
    float mn = fmaxf(m, mo);
    l = l * fexp2(m - mn) + lo * fexp2(mo - mn);
    m = mn;
  }
  if (lane < 16) statp[(size_t)js * 32768 + (size_t)bh * 2048 + i0 + li] = make_float2(m, l);
}

// ---------------- k3: kFused — QK^T + softmax + mix + LN + PV, S in LDS ----------------
// grid (32 i-tiles of 64, 2 b, 4 j-quarters), 512 thr = 8 waves, wave = head.
__global__ __launch_bounds__(512) void kFused(
    const u16* __restrict__ qb, const u16* __restrict__ kb,
    const u16* __restrict__ vtb, const float2* __restrict__ statp,
    const float* __restrict__ Wmix, const float* __restrict__ lng,
    const float* __restrict__ lnb, float* __restrict__ innerF) {
  __shared__ __align__(16) u16 Spk[64 * 512];     // 64KB  p bf16 [i][h][x]
  __shared__ __align__(16) u16 A2h[8 * 64 * 72];  // 72KB  A'' bf16 [g][i][x]
  __shared__ float stMs[64 * 8];                  // 2KB   M = m+log2(l) [i][h]
  const int t = threadIdx.x, lane = t & 63, w = t >> 6;
  const int li = lane & 15, lg = lane >> 4;
  const int ig = blockIdx.x * 64, b = blockIdx.y, j0 = blockIdx.z * 512;

  float wm_[8][8], lng_[8], lnb_[8];   // uniform -> SGPR
#pragma unroll
  for (int h = 0; h < 8; h++)
#pragma unroll
    for (int g = 0; g < 8; g++) wm_[h][g] = Wmix[h * 8 + g];
#pragma unroll
  for (int g = 0; g < 8; g++) { lng_[g] = lng[g]; lnb_[g] = lnb[g]; }

  // stats merge over 8 j-split partials -> stMs[i][h]
  {
    const int i = t >> 3, h = t & 7;
    const size_t idx = ((size_t)(b * 8 + h)) * 2048 + ig + i;
    float m = -1e30f, l = 0.f;
#pragma unroll
    for (int z = 0; z < 8; z++) {
      const float2 a = statp[(size_t)z * 32768 + idx];
      const float mn = fmaxf(m, a.x);
      l = l * fexp2(m - mn) + a.y * fexp2(a.x - mn);
      m = mn;
    }
    stMs[i * 8 + h] = m + flog2(l);
  }

  // Q fragments for head w (held in regs for the whole block)
  bfx8 qf[4][2];
#pragma unroll
  for (int ii = 0; ii < 4; ii++)
#pragma unroll
    for (int ks = 0; ks < 2; ks++)
      qf[ii][ks] = *(const bfx8*)&qb[(((size_t)(b * 8 + w)) * 2048 + ig + ii * 16 + li) * 64
                                     + ks * 32 + lg * 8];
  __syncthreads();
  float stMp[4];
#pragma unroll
  for (int ii = 0; ii < 4; ii++) stMp[ii] = stMs[(ii * 16 + li) * 8 + w];

  f32x4 pacc[4][4] = {};
  const int mixI = t >> 3, mixJ8 = (t & 7) * 8;   // mix-phase position base
  const int mixSwz = (mixI & 7) << 3;

  // K prologue: fragments for tile 0
  bfx8 kf[4][2];
#pragma unroll
  for (int ji = 0; ji < 4; ji++)
#pragma unroll
    for (int ks = 0; ks < 2; ks++)
      kf[ji][ks] = *(const bfx8*)&kb[(((size_t)(b * 8 + w)) * 2048 + j0 + ji * 16 + li) * 64
                                     + ks * 32 + lg * 8];

  for (int jt = j0; jt < j0 + 512; jt += 64) {
    // QK^T + exp + pack to Spk. element: j = jt + ji*16 + lg*4 + r, i = ii*16 + li.
#pragma unroll
    for (int ii = 0; ii < 4; ii++) {
      f32x4 s[4] = {};
#pragma unroll
      for (int ji = 0; ji < 4; ji++) {
        s[ji] = __builtin_amdgcn_mfma_f32_16x16x32_bf16(kf[ji][0], qf[ii][0], s[ji], 0, 0, 0);
        s[ji] = __builtin_amdgcn_mfma_f32_16x16x32_bf16(kf[ji][1], qf[ii][1], s[ji], 0, 0, 0);
      }
      const int i = ii * 16 + li;
      const int swzI = (i & 7) << 3;
#pragma unroll
      for (int ji = 0; ji < 4; ji++) {
        const float p0 = fexp2(s[ji][0] - stMp[ii]);
        const float p1 = fexp2(s[ji][1] - stMp[ii]);
        const float p2 = fexp2(s[ji][2] - stMp[ii]);
        const float p3 = fexp2(s[ji][3] - stMp[ii]);
        const int x = (ji * 16 + lg * 4) ^ swzI;
        *(uint2*)&Spk[i * 512 + w * 64 + x] = make_uint2(cvtpk(p0, p1), cvtpk(p2, p3));
      }
    }
    __syncthreads();   // barrier1: Spk ready
    // T14: V(current) + K(next) issued here -> drained at barrier2 (hidden by mix)
    bfx8 vf0[4], vf1[4];
#pragma unroll
    for (int dt = 0; dt < 4; dt++) {
      vf0[dt] = *(const bfx8*)&vtb[(((size_t)(b * 8 + w)) * 64 + dt * 16 + li) * 2048
                                   + jt + lg * 8];
      vf1[dt] = *(const bfx8*)&vtb[(((size_t)(b * 8 + w)) * 64 + dt * 16 + li) * 2048
                                   + jt + 32 + lg * 8];
    }
    {
      const int jn = (jt + 64 < j0 + 512) ? jt + 64 : j0;
#pragma unroll
      for (int ji = 0; ji < 4; ji++)
#pragma unroll
        for (int ks = 0; ks < 2; ks++)
          kf[ji][ks] = *(const bfx8*)&kb[(((size_t)(b * 8 + w)) * 2048 + jn + ji * 16 + li) * 64
                                         + ks * 32 + lg * 8];
    }
    __builtin_amdgcn_sched_barrier(0);
    // MIX + LN: thread handles 8 positions (i = mixI, j = jt + mixJ8 + 0..7)
    {
      uint4 sv[8];
#pragma unroll
      for (int h = 0; h < 8; h++)
        sv[h] = *(const uint4*)&Spk[mixI * 512 + h * 64 + (mixJ8 ^ mixSwz)];
      u32 ogw[8][4];
      float tmp[8];
#pragma unroll
      for (int hf = 0; hf < 2; hf++) {
        float p[8][4];
#pragma unroll
        for (int h = 0; h < 8; h++) {
          const u32 va = hf ? sv[h].z : sv[h].x;
          const u32 vb = hf ? sv[h].w : sv[h].y;
          union { u32 u; float f; } c0, c1, c2, c3;
          c0.u = va << 16; c1.u = va & 0xffff0000u;
          c2.u = vb << 16; c3.u = vb & 0xffff0000u;
          p[h][0] = c0.f; p[h][1] = c1.f; p[h][2] = c2.f; p[h][3] = c3.f;
        }
#pragma unroll
        for (int e = 0; e < 4; e++) {
          float a_[8]; float sum = 0.f, sumsq = 0.f;
#pragma unroll
          for (int g = 0; g < 8; g++) {
            float acc = 0.f;
#pragma unroll
            for (int h = 0; h < 8; h++) acc = fmaf(p[h][e], wm_[h][g], acc);
            a_[g] = acc; sum += acc; sumsq = fmaf(acc, acc, sumsq);
          }
          const float mu = sum * 0.125f;
          const float var = fmaf(sumsq, 0.125f, -mu * mu);
          const float rs = rsqrtf(var + 1e-5f);
#pragma unroll
          for (int g = 0; g < 8; g++) {
            const float av = fmaf((a_[g] - mu) * rs, lng_[g], lnb_[g]);
            if (e & 1) ogw[g][hf * 2 + (e >> 1)] = cvtpk(tmp[g], av);
            else       tmp[g] = av;
          }
        }
      }
#pragma unroll
      for (int g = 0; g < 8; g++)
        *(uint4*)&A2h[g * 4608 + mixI * 72 + (mixJ8 ^ mixSwz)] =
            make_uint4(ogw[g][0], ogw[g][1], ogw[g][2], ogw[g][3]);
    }
    __syncthreads();   // barrier2: A2h ready; V/K prefetch drains here
    // PV: head w; A = A''[i][j] from A2h, B = V (prefetched under mix).
    // NOTE: no trailing barrier — PV reads A2h; next QK^T writes Spk (disjoint);
    // mix(t+1)'s A2h writes are fenced by barrier1(t+1).
    __builtin_amdgcn_s_setprio(1);
#pragma unroll
    for (int iSub = 0; iSub < 4; iSub++) {
      const bfx8 af0 = *(const bfx8*)&A2h[w * 4608 + (iSub * 16 + li) * 72
                                          + ((lg * 8) ^ ((li & 7) << 3))];
#pragma unroll
      for (int dt = 0; dt < 4; dt++)
        pacc[iSub][dt] = __builtin_amdgcn_mfma_f32_16x16x32_bf16(af0, vf0[dt], pacc[iSub][dt], 0, 0, 0);
    }
#pragma unroll
    for (int iSub = 0; iSub < 4; iSub++) {
      const bfx8 af1 = *(const bfx8*)&A2h[w * 4608 + (iSub * 16 + li) * 72
                                          + ((32 + lg * 8) ^ ((li & 7) << 3))];
#pragma unroll
      for (int dt = 0; dt < 4; dt++)
        pacc[iSub][dt] = __builtin_amdgcn_mfma_f32_16x16x32_bf16(af1, vf1[dt], pacc[iSub][dt], 0, 0, 0);
    }
    __builtin_amdgcn_s_setprio(0);
  }
  // epilogue: f32 atomic partials (4 j-quarter contributions per element)
#pragma unroll
  for (int iSub = 0; iSub < 4; iSub++)
#pragma unroll
    for (int dt = 0; dt < 4; dt++)
#pragma unroll
      for (int r = 0; r < 4; r++)
        atomicAdd(&innerF[((size_t)b * 2048 + ig + iSub * 16 + lg * 4 + r) * 512
                          + w * 64 + dt * 16 + li],
                  pacc[iSub][dt][r]);
}

// ---------------- k4: out = innerF(f32) @ w_out^T + b_out, BM=64 ----------------
// grid 256 linear = 1 block/CU exact; swizzle chunk 32.
__global__ __launch_bounds__(256) void gemm_out(
    const float* __restrict__ A, const float* __restrict__ B,
    float* __restrict__ outf, const float* __restrict__ bias) {
  __shared__ u16 As[64 * 32];
  __shared__ u16 Bs[128 * 32];
  const int bid = blockIdx.x;
  const int swzb = (bid & 7) * 32 + (bid >> 3);
  const int m0 = (swzb >> 2) * 64, n0 = (swzb & 3) * 128;
  const int t = threadIdx.x, lane = t & 63, w = t >> 6;
  const int li = lane & 15, lg = lane >> 4;
  const int rowA = t >> 2, kb8 = (t & 3) * 8;
  f32x4 acc[4][2] = {};
  for (int k0 = 0; k0 < 512; k0 += 32) {
    __syncthreads();
    *(uint4*)&As[rowA * 32 + kb8]        = pk8(&A[(size_t)(m0 + rowA) * 512 + k0 + kb8]);
    *(uint4*)&Bs[rowA * 32 + kb8]        = pk8(&B[(size_t)(n0 + rowA) * 512 + k0 + kb8]);
    *(uint4*)&Bs[(rowA + 64) * 32 + kb8] = pk8(&B[(size_t)(n0 + rowA + 64) * 512 + k0 + kb8]);
    __syncthreads();
    bfx8 af[4], bf_[2];
#pragma unroll
    for (int mi = 0; mi < 4; mi++)
      af[mi] = *(const bfx8*)&As[(mi * 16 + li) * 32 + lg * 8];
#pragma unroll
    for (int ni = 0; ni < 2; ni++)
      bf_[ni] = *(const bfx8*)&Bs[(w * 32 + ni * 16 + li) * 32 + lg * 8];
#pragma unroll
    for (int mi = 0; mi < 4; mi++)
#pragma unroll
      for (int ni = 0; ni < 2; ni++)
        acc[mi][ni] = __builtin_amdgcn_mfma_f32_16x16x32_bf16(af[mi], bf_[ni], acc[mi][ni], 0, 0, 0);
  }
#pragma unroll
  for (int mi = 0; mi < 4; mi++) {
#pragma unroll
    for (int ni = 0; ni < 2; ni++) {
      const int nc  = n0 + w * 32 + ni * 16 + li;
      const int mrb = m0 + mi * 16 + lg * 4;
      const float bv = bias[nc];
#pragma unroll
      for (int r = 0; r < 4; r++)
        outf[(size_t)(mrb + r) * 512 + nc] = acc[mi][ni][r] + bv;
    }
  }
}

// ---------------- host ----------------
extern "C" void kernel_launch(void* const* d_in, const int* in_sizes, int n_in,
                              void* d_out, int out_size, void* d_ws, size_t ws_size,
                              hipStream_t stream) {
  const float* x      = (const float*)d_in[0];
  const float* w_qkv  = (const float*)d_in[1];
  const float* reattn = (const float*)d_in[2];
  const float* ln_g   = (const float*)d_in[3];
  const float* ln_b   = (const float*)d_in[4];
  const float* w_out  = (const float*)d_in[5];
  const float* b_out  = (const float*)d_in[6];
  float* out = (float*)d_out;
  char* ws = (char*)d_ws;
  // ws layout (bytes), ~23.1 MB (proven budget >= 23.9):
  //  [0, 8388608)         innerF f32 (zeroed inside gemm_qkv)
  //  [8388608, 12582912)  qbf [2,8,2048,64] bf16 (scaled)
  //  [12582912,16777216)  kbf
  //  [16777216,20971520)  vtb [2,8,64,2048]
  //  [20971520,23068672)  statp [8][2,8,2048] float2
  float*  innerF= (float*)(ws + 0);
  u16*    qbf   = (u16*)(ws + 8388608);
  u16*    kbf   = (u16*)(ws + 12582912);
  u16*    vtb   = (u16*)(ws + 16777216);
  float2* statp = (float2*)(ws + 20971520);

  gemm_qkv<<<768, 256, 0, stream>>>(x, w_qkv, qbf, kbf, vtb, (float4*)innerF);
  passA<<<4096, 256, 0, stream>>>(qbf, kbf, statp);
  kFused<<<dim3(32, 2, 4), 512, 0, stream>>>(qbf, kbf, vtb, statp, reattn, ln_g, ln_b, innerF);
  gemm_out<<<256, 256, 0, stream>>>(innerF, w_out, out, b_out);
}